// Round 7
// baseline (317.806 us; speedup 1.0000x reference)
//
#include <hip/hip_runtime.h>

// AttnBlock: GroupNorm(4) -> fused qkv 1x1conv -> FUSED flash attention
//            (S^T via mfma(K,Q), exp(s/16-8), block-level P_block relayout, PV
//             with per-wave 32-channel output slice -> V reads amortized 16x)
//            -> combine (4-way j-split merge + 1/l scale) -> proj 1x1conv + residual
// bf16 MFMA 16x16x32 everywhere, fp32 accumulate.
// NOTE: __launch_bounds__ 2nd arg is min BLOCKS/CU (CUDA semantics). (512,2) capped
// VGPR at 128 and spilled oacc to scratch (467MB FETCH). (512,1) -> 256 VGPR budget.

#define HW 4096
#define CCH 256
#define NBATCH 4
#define GN_N (64 * HW)

typedef unsigned short u16;
typedef __attribute__((ext_vector_type(8))) short bf16x8;
typedef __attribute__((ext_vector_type(4))) float f32x4;
typedef __attribute__((ext_vector_type(4))) u16 u16x4;

__device__ __forceinline__ u16 f2bf(float f) {
  unsigned u = __float_as_uint(f);
  u += 0x7fffu + ((u >> 16) & 1u);   // round-to-nearest-even
  return (u16)(u >> 16);
}
__device__ __forceinline__ float bf2f(u16 h) { return __uint_as_float(((unsigned)h) << 16); }

__device__ __forceinline__ void gload_lds16(const void* g, void* l) {
  __builtin_amdgcn_global_load_lds(
      (const __attribute__((address_space(1))) unsigned*)g,
      (__attribute__((address_space(3))) unsigned*)l, 16, 0, 0);
}

// ---------------- GroupNorm stats ----------------
__global__ __launch_bounds__(256) void gn_partial(const float* __restrict__ x,
                                                  float* __restrict__ part) {
  const int bg = blockIdx.y, blk = blockIdx.x, tid = threadIdx.x;
  const float4* X = (const float4*)(x + (size_t)bg * GN_N);
  float s = 0.f, ss = 0.f;
#pragma unroll
  for (int u = 0; u < 8; ++u) {
    float4 v = X[blk * 2048 + u * 256 + tid];
    s += v.x + v.y + v.z + v.w;
    ss += v.x * v.x + v.y * v.y + v.z * v.z + v.w * v.w;
  }
  for (int off = 32; off; off >>= 1) { s += __shfl_xor(s, off); ss += __shfl_xor(ss, off); }
  __shared__ float rs[4], rss[4];
  const int w = tid >> 6;
  if ((tid & 63) == 0) { rs[w] = s; rss[w] = ss; }
  __syncthreads();
  if (tid == 0) {
    part[(bg * 32 + blk) * 2 + 0] = rs[0] + rs[1] + rs[2] + rs[3];
    part[(bg * 32 + blk) * 2 + 1] = rss[0] + rss[1] + rss[2] + rss[3];
  }
}

__global__ void gn_finalize(const float* __restrict__ part, float2* __restrict__ stats) {
  const int t = threadIdx.x;
  if (t < 16) {
    float s = 0.f, ss = 0.f;
    for (int u = 0; u < 32; ++u) { s += part[(t * 32 + u) * 2]; ss += part[(t * 32 + u) * 2 + 1]; }
    const float mean = s * (1.0f / GN_N);
    const float var = ss * (1.0f / GN_N) - mean * mean;
    stats[t] = make_float2(mean, rsqrtf(var + 1e-6f));
  }
}

// ---------------- normalize + transpose -> Ht[b][i][c] bf16 ----------------
__global__ __launch_bounds__(256) void norm_tr(const float* __restrict__ x,
                                               const float2* __restrict__ stats,
                                               const float* __restrict__ gsc,
                                               const float* __restrict__ gbi,
                                               u16* __restrict__ Ht) {
  __shared__ u16 T[64][72];
  const int i0 = blockIdx.x * 64, c0 = blockIdx.y * 64, b = blockIdx.z;
  const int tid = threadIdx.x;
  const int cl = tid >> 4;
  const int il4 = (tid & 15) * 4;
#pragma unroll
  for (int it = 0; it < 4; ++it) {
    const int c = c0 + it * 16 + cl;
    const float2 st = stats[b * 4 + (c >> 6)];
    const float sc = gsc[c] * st.y;
    const float bi = gbi[c] - st.x * sc;
    const float4 v = *(const float4*)&x[((size_t)(b * CCH + c)) * HW + i0 + il4];
    T[il4 + 0][it * 16 + cl] = f2bf(v.x * sc + bi);
    T[il4 + 1][it * 16 + cl] = f2bf(v.y * sc + bi);
    T[il4 + 2][it * 16 + cl] = f2bf(v.z * sc + bi);
    T[il4 + 3][it * 16 + cl] = f2bf(v.w * sc + bi);
  }
  __syncthreads();
  const int il = tid >> 2, cs = (tid & 3) * 16;
  const uint4 a = *(const uint4*)&T[il][cs];
  const uint4 b2 = *(const uint4*)&T[il][cs + 8];
  const size_t o = ((size_t)b * HW + i0 + il) * CCH + c0 + cs;
  *(uint4*)&Ht[o] = a;
  *(uint4*)&Ht[o + 8] = b2;
}

// ---------------- cast weights fp32 -> bf16 ----------------
__global__ __launch_bounds__(256) void wcast(const float* __restrict__ w0, const float* __restrict__ w1,
                                             const float* __restrict__ w2, const float* __restrict__ w3,
                                             u16* __restrict__ dst) {
  const float* src = blockIdx.y == 0 ? w0 : blockIdx.y == 1 ? w1 : blockIdx.y == 2 ? w2 : w3;
  u16* d = dst + (size_t)blockIdx.y * 65536;
  const int idx = (blockIdx.x * 256 + threadIdx.x) * 8;
  const float4 a = *(const float4*)&src[idx];
  const float4 c = *(const float4*)&src[idx + 4];
  uint4 p;
  p.x = (unsigned)f2bf(a.x) | ((unsigned)f2bf(a.y) << 16);
  p.y = (unsigned)f2bf(a.z) | ((unsigned)f2bf(a.w) << 16);
  p.z = (unsigned)f2bf(c.x) | ((unsigned)f2bf(c.y) << 16);
  p.w = (unsigned)f2bf(c.z) | ((unsigned)f2bf(c.w) << 16);
  *(uint4*)&d[idx] = p;
}

// ---------------- NT GEMM (QKV + proj), 2-phase dbuf, as validated ----------------
template <int EPI, bool HASB>
__global__ __launch_bounds__(256) void gemm2(
    const u16* __restrict__ A, int lda, long sA,
    const u16* __restrict__ Bm, int ldb, long sB,
    void* __restrict__ O0, int ldo, long sO,
    void* __restrict__ O1, void* __restrict__ O2,
    const float* __restrict__ b0, const float* __restrict__ b1, const float* __restrict__ b2,
    const float* __restrict__ aux, long sAux,
    float scale, int K) {
  __shared__ char lsA[32768], lsB[32768];
  int bx, by, bz;
  {
    const int nx = gridDim.x, ny = gridDim.y;
    const int lin = blockIdx.x + nx * (blockIdx.y + ny * blockIdx.z);
    const int q = (nx * ny * (int)gridDim.z) >> 3;
    const int wg = (lin & 7) * q + (lin >> 3);
    bx = wg % nx; const int t2 = wg / nx; by = t2 % ny; bz = t2 / ny;
  }
  const int tid = threadIdx.x;
  const int w = tid >> 6, l = tid & 63;
  const int wm = w >> 1, wn = w & 1;
  const int m0 = by * 128, n0 = bx * 128;
  const u16* Ab = A + (size_t)bz * sA;
  const u16* Bb = Bm + (size_t)bz * sB;

  f32x4 acc[4][4];
#pragma unroll
  for (int i = 0; i < 4; ++i)
#pragma unroll
    for (int j = 0; j < 4; ++j)
#pragma unroll
      for (int q2 = 0; q2 < 4; ++q2) acc[i][j][q2] = 0.f;

  auto stage = [&](int buf, int k0) {
#pragma unroll
    for (int s = 0; s < 4; ++s) {
      const int o = s * 4096 + tid * 16;
      const int r = o >> 7;
      const int c = ((o >> 4) & 7) ^ (r & 7);
      const int ke = c * 8;
      gload_lds16(Ab + (size_t)(m0 + r) * lda + k0 + ke, lsA + buf * 16384 + s * 4096 + w * 1024);
      gload_lds16(Bb + (size_t)(n0 + r) * ldb + k0 + ke, lsB + buf * 16384 + s * 4096 + w * 1024);
    }
  };

  const int nt = K >> 6;
  stage(0, 0);
  asm volatile("s_waitcnt vmcnt(0)" ::: "memory");
  __syncthreads();
  for (int t = 0; t < nt; ++t) {
    const int cur = t & 1;
    if (t + 1 < nt) stage(cur ^ 1, (t + 1) << 6);
#pragma unroll
    for (int kk = 0; kk < 2; ++kk) {
      bf16x8 aF[4], bF[4];
#pragma unroll
      for (int mi = 0; mi < 4; ++mi) {
        const int r = wm * 64 + mi * 16 + (l & 15);
        const int cc = (kk * 4 + (l >> 4)) ^ (r & 7);
        aF[mi] = *(const bf16x8*)(lsA + cur * 16384 + r * 128 + cc * 16);
      }
#pragma unroll
      for (int ni = 0; ni < 4; ++ni) {
        const int r = wn * 64 + ni * 16 + (l & 15);
        const int cc = (kk * 4 + (l >> 4)) ^ (r & 7);
        bF[ni] = *(const bf16x8*)(lsB + cur * 16384 + r * 128 + cc * 16);
      }
#pragma unroll
      for (int mi = 0; mi < 4; ++mi)
#pragma unroll
        for (int ni = 0; ni < 4; ++ni)
          acc[mi][ni] = __builtin_amdgcn_mfma_f32_16x16x32_bf16(aF[mi], bF[ni], acc[mi][ni], 0, 0, 0);
    }
    asm volatile("s_waitcnt vmcnt(0)" ::: "memory");
    __syncthreads();
  }

  const int lc = l & 15;
  const int lr4 = (l >> 4) * 4;   // C/D: col=lane&15, row=(lane>>4)*4+reg

  if (EPI == 5) {
    const int sel = m0 >> 8;   // 0:Q 1:K 2:V
    const float* bs = sel == 0 ? b0 : sel == 1 ? b1 : b2;
#pragma unroll
    for (int mi = 0; mi < 4; ++mi) {
      const int mg = m0 + wm * 64 + mi * 16 + lr4;
      const int mloc = mg & 255;
      const float4 bv = *(const float4*)&bs[mloc];
      float bb4[4] = {bv.x, bv.y, bv.z, bv.w};
#pragma unroll
      for (int ni = 0; ni < 4; ++ni) {
        const int n = n0 + wn * 64 + ni * 16 + lc;
        if (sel == 2) {
          u16* V = (u16*)O2 + (size_t)bz * sO;
#pragma unroll
          for (int q2 = 0; q2 < 4; ++q2) V[(size_t)(mloc + q2) * HW + n] = f2bf(acc[mi][ni][q2] + bb4[q2]);
        } else {
          u16* Oq = (u16*)(sel == 0 ? O0 : O1) + (size_t)bz * sO;
          u16x4 pk;
#pragma unroll
          for (int q2 = 0; q2 < 4; ++q2) pk[q2] = f2bf(acc[mi][ni][q2] + bb4[q2]);
          *(u16x4*)&Oq[(size_t)n * CCH + mloc] = pk;
        }
      }
    }
  } else {   // EPI == 2: fp32 out + bias + residual
    float* O = (float*)O0 + (size_t)bz * sO;
    const float* R = aux + (size_t)bz * sAux;
#pragma unroll
    for (int mi = 0; mi < 4; ++mi) {
      const int mb = m0 + wm * 64 + mi * 16 + lr4;
      float bb4[4] = {0.f, 0.f, 0.f, 0.f};
      if (HASB) {
        const float4 bv = *(const float4*)&b0[mb];
        bb4[0] = bv.x; bb4[1] = bv.y; bb4[2] = bv.z; bb4[3] = bv.w;
      }
#pragma unroll
      for (int ni = 0; ni < 4; ++ni) {
        const int n = n0 + wn * 64 + ni * 16 + lc;
#pragma unroll
        for (int q2 = 0; q2 < 4; ++q2)
          O[(size_t)(mb + q2) * ldo + n] = acc[mi][ni][q2] * scale + bb4[q2] + R[(size_t)(mb + q2) * ldo + n];
      }
    }
  }
}

// ---------------- fused flash attention ----------------
// Grid: 256 blocks x 512 thr (8 waves). bid: it=bid>>4 (256-row i-tile), b=(bid>>2)&3, js=bid&3.
// Per t-step (KVBLK=64 j), two 32-j halves:
//   S^T half = mfma(K, Q) (each wave: its 32 i-rows) -> exp -> pack to block P_block[256 i][32 j]
//   -> barrier -> PV: wave w owns channels [w*32, w*32+32) for ALL 256 i (V frags reused 16x).
// Raw s_barrier + writer-side lgkmcnt(0): staging vmcnt NOT drained mid-t (only at t end).
#define LBUF 65536            // K 32KB | V 32KB per buffer
__global__ __launch_bounds__(512, 1) void attn_fused(
    const u16* __restrict__ Qt, const u16* __restrict__ Kt, const u16* __restrict__ Vv,
    float* __restrict__ Opart, float* __restrict__ Rpart) {
  __shared__ __attribute__((aligned(16))) char lds[2 * LBUF];
  __shared__ __attribute__((aligned(16))) unsigned P_block[256][20];  // stride 20 dw: conflict-free b128 rows
  const int bid = blockIdx.x;
  const int it = bid >> 4, b = (bid >> 2) & 3, js = bid & 3;
  const int tid = threadIdx.x, w = tid >> 6, l = tid & 63;
  const int g = l >> 4, base = l & 15;
  const u16* Qb = Qt + (size_t)b * HW * CCH;
  const u16* Kb = Kt + (size_t)b * HW * CCH;
  const u16* Vb = Vv + (size_t)b * CCH * HW;
  const int iw0 = it * 256 + w * 32;

  // Q fragments: q[bi][kc], row = iw0 + bi*16 + base, k = kc*32 + g*8 + e
  bf16x8 q[2][8];
#pragma unroll
  for (int bi = 0; bi < 2; ++bi)
#pragma unroll
    for (int kc = 0; kc < 8; ++kc)
      q[bi][kc] = *(const bf16x8*)&Qb[(size_t)(iw0 + bi * 16 + base) * CCH + kc * 32 + g * 8];

  f32x4 oacc[16][2];   // [i-frag fi][c-frag cf]: O[it*256+fi*16+g*4+r][w*32+cf*16+base]
#pragma unroll
  for (int fi = 0; fi < 16; ++fi)
#pragma unroll
    for (int cf = 0; cf < 2; ++cf)
#pragma unroll
      for (int r = 0; r < 4; ++r) oacc[fi][cf][r] = 0.f;
  float rsum[2] = {0.f, 0.f};

  auto stage = [&](int buf, int j0) {
    char* Kl = lds + buf * LBUF;
    char* Vl = Kl + 32768;
#pragma unroll
    for (int s = 0; s < 8; ++s) {
      const int i = w * 8 + s;   // 0..63 (wave-uniform selector)
      if (i < 32) {
        // K-tile [64 rows][32 chunks of 16B], source-swizzled: phys c5 holds logical c5^(row&7)
        const int row = i * 2 + (l >> 5);
        const int c5 = l & 31;
        gload_lds16(Kb + (size_t)(j0 + row) * CCH + ((c5 ^ (row & 7)) * 8), Kl + i * 1024);
      } else {
        // V-tile [8 jg][256 c][16B]: slot (jg, cc) <- V[cc][j0 + jg*8 .. +7]
        const int jj = i - 32;
        const int jg = jj >> 2;
        const int cc = (jj & 3) * 64 + l;
        gload_lds16(Vb + (size_t)cc * HW + j0 + jg * 8, Vl + jg * 4096 + (jj & 3) * 1024);
      }
    }
  };

  const int j0base = js * 1024;
  const int NT = 16;   // 1024 / 64
  stage(0, j0base);
  asm volatile("s_waitcnt vmcnt(0)" ::: "memory");
  __builtin_amdgcn_s_barrier();

  for (int t = 0; t < NT; ++t) {
    const int cur = t & 1;
    if (t + 1 < NT) stage(cur ^ 1, j0base + (t + 1) * 64);
    const char* Kl = lds + cur * LBUF;
    const char* Vl = Kl + 32768;
#pragma unroll
    for (int h = 0; h < 2; ++h) {
      // ---- S^T half: j = h*32 + [0,32), this wave's 32 i-rows ----
      f32x4 sacc[2][2];   // [mjl][bi]
#pragma unroll
      for (int mjl = 0; mjl < 2; ++mjl)
#pragma unroll
        for (int bi = 0; bi < 2; ++bi)
#pragma unroll
          for (int r = 0; r < 4; ++r) sacc[mjl][bi][r] = 0.f;
      __builtin_amdgcn_s_setprio(1);
#pragma unroll
      for (int kc = 0; kc < 8; ++kc) {
        bf16x8 kf[2];
#pragma unroll
        for (int mjl = 0; mjl < 2; ++mjl) {
          const int row = h * 32 + mjl * 16 + base;
          const int c5 = (kc * 4 + g) ^ (row & 7);
          kf[mjl] = *(const bf16x8*)(Kl + row * 512 + c5 * 16);
        }
#pragma unroll
        for (int mjl = 0; mjl < 2; ++mjl)
#pragma unroll
          for (int bi = 0; bi < 2; ++bi)
            sacc[mjl][bi] = __builtin_amdgcn_mfma_f32_16x16x32_bf16(kf[mjl], q[bi][kc], sacc[mjl][bi], 0, 0, 0);
      }
      __builtin_amdgcn_s_setprio(0);
      // ---- exp + pack; lane holds P'[jloc = mjl*16+4g+r][i = iw0+bi*16+base] ----
#pragma unroll
      for (int bi = 0; bi < 2; ++bi) {
        const int iL = w * 32 + bi * 16 + base;
#pragma unroll
        for (int mjl = 0; mjl < 2; ++mjl) {
          const float p0 = __expf(sacc[mjl][bi][0] * 0.0625f - 8.0f);
          const float p1 = __expf(sacc[mjl][bi][1] * 0.0625f - 8.0f);
          const float p2 = __expf(sacc[mjl][bi][2] * 0.0625f - 8.0f);
          const float p3 = __expf(sacc[mjl][bi][3] * 0.0625f - 8.0f);
          const u16 e0 = f2bf(p0), e1 = f2bf(p1), e2 = f2bf(p2), e3 = f2bf(p3);
          rsum[bi] += (bf2f(e0) + bf2f(e1)) + (bf2f(e2) + bf2f(e3));
          P_block[iL][mjl * 8 + g * 2 + 0] = (unsigned)e0 | ((unsigned)e1 << 16);
          P_block[iL][mjl * 8 + g * 2 + 1] = (unsigned)e2 | ((unsigned)e3 << 16);
        }
      }
      asm volatile("s_waitcnt lgkmcnt(0)" ::: "memory");   // drain own P writes
      __builtin_amdgcn_sched_barrier(0);
      __builtin_amdgcn_s_barrier();                        // P_block visible to all waves
      // ---- PV: wave w computes O[all 256 i][w*32 .. w*32+32) over this 32-j chunk ----
      bf16x8 vf[2];
#pragma unroll
      for (int cf = 0; cf < 2; ++cf)
        vf[cf] = *(const bf16x8*)(Vl + (h * 4 + g) * 4096 + (w * 32 + cf * 16 + base) * 16);
      __builtin_amdgcn_s_setprio(1);
#pragma unroll
      for (int fi = 0; fi < 16; ++fi) {
        const bf16x8 af = *(const bf16x8*)&P_block[fi * 16 + base][g * 4];
#pragma unroll
        for (int cf = 0; cf < 2; ++cf)
          oacc[fi][cf] = __builtin_amdgcn_mfma_f32_16x16x32_bf16(af, vf[cf], oacc[fi][cf], 0, 0, 0);
      }
      __builtin_amdgcn_s_setprio(0);
      if (h == 0) {
        asm volatile("s_waitcnt lgkmcnt(0)" ::: "memory");  // PV reads done before h=1 pack overwrites
        __builtin_amdgcn_sched_barrier(0);
        __builtin_amdgcn_s_barrier();
      }
    }
    asm volatile("s_waitcnt vmcnt(0) lgkmcnt(0)" ::: "memory");  // staged tile ready; PV1 reads done
    __builtin_amdgcn_sched_barrier(0);
    __builtin_amdgcn_s_barrier();
  }

  // ---- epilogue: row-sum partials + O partials (f32) ----
  rsum[0] += __shfl_xor(rsum[0], 16); rsum[0] += __shfl_xor(rsum[0], 32);
  rsum[1] += __shfl_xor(rsum[1], 16); rsum[1] += __shfl_xor(rsum[1], 32);
  if (l < 16) {
    Rpart[(size_t)js * 16384 + b * HW + iw0 + 0 * 16 + l] = rsum[0];
    Rpart[(size_t)js * 16384 + b * HW + iw0 + 1 * 16 + l] = rsum[1];
  }
  float* Op = Opart + (size_t)js * 16384 * CCH + (size_t)b * HW * CCH + (size_t)it * 256 * CCH;
#pragma unroll
  for (int fi = 0; fi < 16; ++fi) {
#pragma unroll
    for (int cf = 0; cf < 2; ++cf) {
      const int c = w * 32 + cf * 16 + base;
#pragma unroll
      for (int r = 0; r < 4; ++r)
        Op[(size_t)(fi * 16 + g * 4 + r) * CCH + c] = oacc[fi][cf][r];
    }
  }
}

// ---------------- combine: Ot = bf16(sum_js O / sum_js r) ----------------
__global__ __launch_bounds__(256) void attn_combine(const float* __restrict__ Op,
                                                    const float* __restrict__ Rp,
                                                    u16* __restrict__ Ot) {
  const int idx = blockIdx.x * 256 + threadIdx.x;   // 1M threads
  const int row = idx >> 6;                         // b*4096 + i
  const int c4 = (idx & 63) * 4;
  float4 s = make_float4(0.f, 0.f, 0.f, 0.f);
  float rs = 0.f;
#pragma unroll
  for (int js = 0; js < 4; ++js) {
    const float4 o = *(const float4*)&Op[((size_t)js * 16384 + row) * CCH + c4];
    s.x += o.x; s.y += o.y; s.z += o.z; s.w += o.w;
    rs += Rp[(size_t)js * 16384 + row];
  }
  const float inv = 1.0f / rs;
  u16x4 r;
  r[0] = f2bf(s.x * inv);
  r[1] = f2bf(s.y * inv);
  r[2] = f2bf(s.z * inv);
  r[3] = f2bf(s.w * inv);
  *(u16x4*)&Ot[(size_t)row * CCH + c4] = r;
}

extern "C" void kernel_launch(void* const* d_in, const int* in_sizes, int n_in,
                              void* d_out, int out_size, void* d_ws, size_t ws_size,
                              hipStream_t stream) {
  const float* x   = (const float*)d_in[0];
  const float* gsc = (const float*)d_in[1];
  const float* gbi = (const float*)d_in[2];
  const float* wq  = (const float*)d_in[3];
  const float* bq  = (const float*)d_in[4];
  const float* wk  = (const float*)d_in[5];
  const float* bk  = (const float*)d_in[6];
  const float* wv  = (const float*)d_in[7];
  const float* bv  = (const float*)d_in[8];
  const float* wp  = (const float*)d_in[9];
  const float* bp  = (const float*)d_in[10];
  float* out = (float*)d_out;

  char* ws = (char*)d_ws;
  size_t off = 0;
  auto alloc = [&](size_t bytes) {
    size_t o = off; off = (off + bytes + 255) & ~(size_t)255; return o;
  };
  const size_t szMat = (size_t)NBATCH * HW * CCH * 2;   // 8.4MB
  u16* W      = (u16*)(ws + alloc(4 * 65536 * 2));
  float* pgn  = (float*)(ws + alloc(16 * 32 * 2 * 4));
  float2* st  = (float2*)(ws + alloc(16 * 8));
  u16* Ht = (u16*)(ws + alloc(szMat));   // [b][i][c]
  u16* Qt = (u16*)(ws + alloc(szMat));   // [b][i][c]
  u16* Kt = (u16*)(ws + alloc(szMat));   // [b][j][c]
  u16* Vv = (u16*)(ws + alloc(szMat));   // [b][c][j]
  u16* Ot = (u16*)(ws + alloc(szMat));   // [b][i][c]
  float* Opart = (float*)(ws + alloc((size_t)4 * 16384 * CCH * 4));  // 67MB
  float* Rpart = (float*)(ws + alloc((size_t)4 * 16384 * 4));        // 256KB

  const long sM = (long)HW * CCH;

  wcast<<<dim3(32, 4), 256, 0, stream>>>(wq, wk, wv, wp, W);
  gn_partial<<<dim3(32, 16), 256, 0, stream>>>(x, pgn);
  gn_finalize<<<1, 64, 0, stream>>>(pgn, st);
  norm_tr<<<dim3(HW / 64, CCH / 64, NBATCH), 256, 0, stream>>>(x, st, gsc, gbi, Ht);

  // fused QKV: A = [Wq;Wk;Wv] (768x256), B = Ht -> Qt [i][c], Kt [j][c], Vv [c][j]
  gemm2<5, true><<<dim3(32, 6, NBATCH), 256, 0, stream>>>(
      W, 256, 0, Ht, 256, sM, Qt, 256, sM, Kt, Vv, bq, bk, bv, nullptr, 0, 1.f, 256);

  // fused attention
  attn_fused<<<256, 512, 0, stream>>>(Qt, Kt, Vv, Opart, Rpart);
  attn_combine<<<4096, 256, 0, stream>>>(Opart, Rpart, Ot);

  // out[c][i] = Wp . Ot^T + bp + x
  gemm2<2, true><<<dim3(32, 2, NBATCH), 256, 0, stream>>>(
      W + 3 * 65536, 256, 0, Ot, 256, sM, out, HW, (long)CCH * HW, nullptr, nullptr,
      bp, nullptr, nullptr, x, (long)CCH * HW, 1.f, 256);
}

// Round 8
// 317.267 us; speedup vs baseline: 1.0017x; 1.0017x over previous
//
#include <hip/hip_runtime.h>

// AttnBlock: GroupNorm(4) -> fused qkv 1x1conv -> FUSED flash attention
//            (S^T via mfma(K,Q), exp(s/16-8), block-level P_block relayout, PV
//             with per-wave 32-channel output slice -> V reads amortized 16x)
//            -> combine (4-way j-split merge + 1/l scale) -> proj 1x1conv + residual
// bf16 MFMA 16x16x32 everywhere, fp32 accumulate.
// REGISTER CAP: hipcc's default heuristic targets 4 waves/EU for 512-thread kernels
// -> 128-VGPR cap -> oacc spilled to scratch (467MB HBM traffic, rounds 6-7).
// amdgpu_waves_per_eu(2,2) pins 2 waves/EU -> 256-VGPR budget, no spill.

#define HW 4096
#define CCH 256
#define NBATCH 4
#define GN_N (64 * HW)

typedef unsigned short u16;
typedef __attribute__((ext_vector_type(8))) short bf16x8;
typedef __attribute__((ext_vector_type(4))) float f32x4;
typedef __attribute__((ext_vector_type(4))) u16 u16x4;

__device__ __forceinline__ u16 f2bf(float f) {
  unsigned u = __float_as_uint(f);
  u += 0x7fffu + ((u >> 16) & 1u);   // round-to-nearest-even
  return (u16)(u >> 16);
}
__device__ __forceinline__ float bf2f(u16 h) { return __uint_as_float(((unsigned)h) << 16); }

__device__ __forceinline__ void gload_lds16(const void* g, void* l) {
  __builtin_amdgcn_global_load_lds(
      (const __attribute__((address_space(1))) unsigned*)g,
      (__attribute__((address_space(3))) unsigned*)l, 16, 0, 0);
}

// ---------------- GroupNorm stats ----------------
__global__ __launch_bounds__(256) void gn_partial(const float* __restrict__ x,
                                                  float* __restrict__ part) {
  const int bg = blockIdx.y, blk = blockIdx.x, tid = threadIdx.x;
  const float4* X = (const float4*)(x + (size_t)bg * GN_N);
  float s = 0.f, ss = 0.f;
#pragma unroll
  for (int u = 0; u < 8; ++u) {
    float4 v = X[blk * 2048 + u * 256 + tid];
    s += v.x + v.y + v.z + v.w;
    ss += v.x * v.x + v.y * v.y + v.z * v.z + v.w * v.w;
  }
  for (int off = 32; off; off >>= 1) { s += __shfl_xor(s, off); ss += __shfl_xor(ss, off); }
  __shared__ float rs[4], rss[4];
  const int w = tid >> 6;
  if ((tid & 63) == 0) { rs[w] = s; rss[w] = ss; }
  __syncthreads();
  if (tid == 0) {
    part[(bg * 32 + blk) * 2 + 0] = rs[0] + rs[1] + rs[2] + rs[3];
    part[(bg * 32 + blk) * 2 + 1] = rss[0] + rss[1] + rss[2] + rss[3];
  }
}

__global__ void gn_finalize(const float* __restrict__ part, float2* __restrict__ stats) {
  const int t = threadIdx.x;
  if (t < 16) {
    float s = 0.f, ss = 0.f;
    for (int u = 0; u < 32; ++u) { s += part[(t * 32 + u) * 2]; ss += part[(t * 32 + u) * 2 + 1]; }
    const float mean = s * (1.0f / GN_N);
    const float var = ss * (1.0f / GN_N) - mean * mean;
    stats[t] = make_float2(mean, rsqrtf(var + 1e-6f));
  }
}

// ---------------- normalize + transpose -> Ht[b][i][c] bf16 ----------------
__global__ __launch_bounds__(256) void norm_tr(const float* __restrict__ x,
                                               const float2* __restrict__ stats,
                                               const float* __restrict__ gsc,
                                               const float* __restrict__ gbi,
                                               u16* __restrict__ Ht) {
  __shared__ u16 T[64][72];
  const int i0 = blockIdx.x * 64, c0 = blockIdx.y * 64, b = blockIdx.z;
  const int tid = threadIdx.x;
  const int cl = tid >> 4;
  const int il4 = (tid & 15) * 4;
#pragma unroll
  for (int it = 0; it < 4; ++it) {
    const int c = c0 + it * 16 + cl;
    const float2 st = stats[b * 4 + (c >> 6)];
    const float sc = gsc[c] * st.y;
    const float bi = gbi[c] - st.x * sc;
    const float4 v = *(const float4*)&x[((size_t)(b * CCH + c)) * HW + i0 + il4];
    T[il4 + 0][it * 16 + cl] = f2bf(v.x * sc + bi);
    T[il4 + 1][it * 16 + cl] = f2bf(v.y * sc + bi);
    T[il4 + 2][it * 16 + cl] = f2bf(v.z * sc + bi);
    T[il4 + 3][it * 16 + cl] = f2bf(v.w * sc + bi);
  }
  __syncthreads();
  const int il = tid >> 2, cs = (tid & 3) * 16;
  const uint4 a = *(const uint4*)&T[il][cs];
  const uint4 b2 = *(const uint4*)&T[il][cs + 8];
  const size_t o = ((size_t)b * HW + i0 + il) * CCH + c0 + cs;
  *(uint4*)&Ht[o] = a;
  *(uint4*)&Ht[o + 8] = b2;
}

// ---------------- cast weights fp32 -> bf16 ----------------
__global__ __launch_bounds__(256) void wcast(const float* __restrict__ w0, const float* __restrict__ w1,
                                             const float* __restrict__ w2, const float* __restrict__ w3,
                                             u16* __restrict__ dst) {
  const float* src = blockIdx.y == 0 ? w0 : blockIdx.y == 1 ? w1 : blockIdx.y == 2 ? w2 : w3;
  u16* d = dst + (size_t)blockIdx.y * 65536;
  const int idx = (blockIdx.x * 256 + threadIdx.x) * 8;
  const float4 a = *(const float4*)&src[idx];
  const float4 c = *(const float4*)&src[idx + 4];
  uint4 p;
  p.x = (unsigned)f2bf(a.x) | ((unsigned)f2bf(a.y) << 16);
  p.y = (unsigned)f2bf(a.z) | ((unsigned)f2bf(a.w) << 16);
  p.z = (unsigned)f2bf(c.x) | ((unsigned)f2bf(c.y) << 16);
  p.w = (unsigned)f2bf(c.z) | ((unsigned)f2bf(c.w) << 16);
  *(uint4*)&d[idx] = p;
}

// ---------------- NT GEMM (QKV + proj), 2-phase dbuf, as validated ----------------
template <int EPI, bool HASB>
__global__ __launch_bounds__(256) void gemm2(
    const u16* __restrict__ A, int lda, long sA,
    const u16* __restrict__ Bm, int ldb, long sB,
    void* __restrict__ O0, int ldo, long sO,
    void* __restrict__ O1, void* __restrict__ O2,
    const float* __restrict__ b0, const float* __restrict__ b1, const float* __restrict__ b2,
    const float* __restrict__ aux, long sAux,
    float scale, int K) {
  __shared__ char lsA[32768], lsB[32768];
  int bx, by, bz;
  {
    const int nx = gridDim.x, ny = gridDim.y;
    const int lin = blockIdx.x + nx * (blockIdx.y + ny * blockIdx.z);
    const int q = (nx * ny * (int)gridDim.z) >> 3;
    const int wg = (lin & 7) * q + (lin >> 3);
    bx = wg % nx; const int t2 = wg / nx; by = t2 % ny; bz = t2 / ny;
  }
  const int tid = threadIdx.x;
  const int w = tid >> 6, l = tid & 63;
  const int wm = w >> 1, wn = w & 1;
  const int m0 = by * 128, n0 = bx * 128;
  const u16* Ab = A + (size_t)bz * sA;
  const u16* Bb = Bm + (size_t)bz * sB;

  f32x4 acc[4][4];
#pragma unroll
  for (int i = 0; i < 4; ++i)
#pragma unroll
    for (int j = 0; j < 4; ++j)
#pragma unroll
      for (int q2 = 0; q2 < 4; ++q2) acc[i][j][q2] = 0.f;

  auto stage = [&](int buf, int k0) {
#pragma unroll
    for (int s = 0; s < 4; ++s) {
      const int o = s * 4096 + tid * 16;
      const int r = o >> 7;
      const int c = ((o >> 4) & 7) ^ (r & 7);
      const int ke = c * 8;
      gload_lds16(Ab + (size_t)(m0 + r) * lda + k0 + ke, lsA + buf * 16384 + s * 4096 + w * 1024);
      gload_lds16(Bb + (size_t)(n0 + r) * ldb + k0 + ke, lsB + buf * 16384 + s * 4096 + w * 1024);
    }
  };

  const int nt = K >> 6;
  stage(0, 0);
  asm volatile("s_waitcnt vmcnt(0)" ::: "memory");
  __syncthreads();
  for (int t = 0; t < nt; ++t) {
    const int cur = t & 1;
    if (t + 1 < nt) stage(cur ^ 1, (t + 1) << 6);
#pragma unroll
    for (int kk = 0; kk < 2; ++kk) {
      bf16x8 aF[4], bF[4];
#pragma unroll
      for (int mi = 0; mi < 4; ++mi) {
        const int r = wm * 64 + mi * 16 + (l & 15);
        const int cc = (kk * 4 + (l >> 4)) ^ (r & 7);
        aF[mi] = *(const bf16x8*)(lsA + cur * 16384 + r * 128 + cc * 16);
      }
#pragma unroll
      for (int ni = 0; ni < 4; ++ni) {
        const int r = wn * 64 + ni * 16 + (l & 15);
        const int cc = (kk * 4 + (l >> 4)) ^ (r & 7);
        bF[ni] = *(const bf16x8*)(lsB + cur * 16384 + r * 128 + cc * 16);
      }
#pragma unroll
      for (int mi = 0; mi < 4; ++mi)
#pragma unroll
        for (int ni = 0; ni < 4; ++ni)
          acc[mi][ni] = __builtin_amdgcn_mfma_f32_16x16x32_bf16(aF[mi], bF[ni], acc[mi][ni], 0, 0, 0);
    }
    asm volatile("s_waitcnt vmcnt(0)" ::: "memory");
    __syncthreads();
  }

  const int lc = l & 15;
  const int lr4 = (l >> 4) * 4;   // C/D: col=lane&15, row=(lane>>4)*4+reg

  if (EPI == 5) {
    const int sel = m0 >> 8;   // 0:Q 1:K 2:V
    const float* bs = sel == 0 ? b0 : sel == 1 ? b1 : b2;
#pragma unroll
    for (int mi = 0; mi < 4; ++mi) {
      const int mg = m0 + wm * 64 + mi * 16 + lr4;
      const int mloc = mg & 255;
      const float4 bv = *(const float4*)&bs[mloc];
      float bb4[4] = {bv.x, bv.y, bv.z, bv.w};
#pragma unroll
      for (int ni = 0; ni < 4; ++ni) {
        const int n = n0 + wn * 64 + ni * 16 + lc;
        if (sel == 2) {
          u16* V = (u16*)O2 + (size_t)bz * sO;
#pragma unroll
          for (int q2 = 0; q2 < 4; ++q2) V[(size_t)(mloc + q2) * HW + n] = f2bf(acc[mi][ni][q2] + bb4[q2]);
        } else {
          u16* Oq = (u16*)(sel == 0 ? O0 : O1) + (size_t)bz * sO;
          u16x4 pk;
#pragma unroll
          for (int q2 = 0; q2 < 4; ++q2) pk[q2] = f2bf(acc[mi][ni][q2] + bb4[q2]);
          *(u16x4*)&Oq[(size_t)n * CCH + mloc] = pk;
        }
      }
    }
  } else {   // EPI == 2: fp32 out + bias + residual
    float* O = (float*)O0 + (size_t)bz * sO;
    const float* R = aux + (size_t)bz * sAux;
#pragma unroll
    for (int mi = 0; mi < 4; ++mi) {
      const int mb = m0 + wm * 64 + mi * 16 + lr4;
      float bb4[4] = {0.f, 0.f, 0.f, 0.f};
      if (HASB) {
        const float4 bv = *(const float4*)&b0[mb];
        bb4[0] = bv.x; bb4[1] = bv.y; bb4[2] = bv.z; bb4[3] = bv.w;
      }
#pragma unroll
      for (int ni = 0; ni < 4; ++ni) {
        const int n = n0 + wn * 64 + ni * 16 + lc;
#pragma unroll
        for (int q2 = 0; q2 < 4; ++q2)
          O[(size_t)(mb + q2) * ldo + n] = acc[mi][ni][q2] * scale + bb4[q2] + R[(size_t)(mb + q2) * ldo + n];
      }
    }
  }
}

// ---------------- fused flash attention ----------------
// Grid: 256 blocks x 512 thr (8 waves). bid: it=bid>>4 (256-row i-tile), b=(bid>>2)&3, js=bid&3.
// Per t-step (KVBLK=64 j), two 32-j halves:
//   S^T half = mfma(K, Q) (each wave: its 32 i-rows) -> exp -> pack to block P_block[256 i][32 j]
//   -> barrier -> PV: wave w owns channels [w*32, w*32+32) for ALL 256 i (V frags reused 16x).
// Raw s_barrier + writer-side lgkmcnt(0): staging vmcnt NOT drained mid-t (only at t end).
#define LBUF 65536            // K 32KB | V 32KB per buffer
__global__ __launch_bounds__(512)
__attribute__((amdgpu_waves_per_eu(2, 2)))
void attn_fused(
    const u16* __restrict__ Qt, const u16* __restrict__ Kt, const u16* __restrict__ Vv,
    float* __restrict__ Opart, float* __restrict__ Rpart) {
  __shared__ __attribute__((aligned(16))) char lds[2 * LBUF];
  __shared__ __attribute__((aligned(16))) unsigned P_block[256][20];  // stride 20 dw: conflict-free b128 rows
  const int bid = blockIdx.x;
  const int it = bid >> 4, b = (bid >> 2) & 3, js = bid & 3;
  const int tid = threadIdx.x, w = tid >> 6, l = tid & 63;
  const int g = l >> 4, base = l & 15;
  const u16* Qb = Qt + (size_t)b * HW * CCH;
  const u16* Kb = Kt + (size_t)b * HW * CCH;
  const u16* Vb = Vv + (size_t)b * CCH * HW;
  const int iw0 = it * 256 + w * 32;

  // Q fragments: q[bi][kc], row = iw0 + bi*16 + base, k = kc*32 + g*8 + e
  bf16x8 q[2][8];
#pragma unroll
  for (int bi = 0; bi < 2; ++bi)
#pragma unroll
    for (int kc = 0; kc < 8; ++kc)
      q[bi][kc] = *(const bf16x8*)&Qb[(size_t)(iw0 + bi * 16 + base) * CCH + kc * 32 + g * 8];

  f32x4 oacc[16][2];   // [i-frag fi][c-frag cf]: O[it*256+fi*16+g*4+r][w*32+cf*16+base]
#pragma unroll
  for (int fi = 0; fi < 16; ++fi)
#pragma unroll
    for (int cf = 0; cf < 2; ++cf)
#pragma unroll
      for (int r = 0; r < 4; ++r) oacc[fi][cf][r] = 0.f;
  float rsum[2] = {0.f, 0.f};

  auto stage = [&](int buf, int j0) {
    char* Kl = lds + buf * LBUF;
    char* Vl = Kl + 32768;
#pragma unroll
    for (int s = 0; s < 8; ++s) {
      const int i = w * 8 + s;   // 0..63 (wave-uniform selector)
      if (i < 32) {
        // K-tile [64 rows][32 chunks of 16B], source-swizzled: phys c5 holds logical c5^(row&7)
        const int row = i * 2 + (l >> 5);
        const int c5 = l & 31;
        gload_lds16(Kb + (size_t)(j0 + row) * CCH + ((c5 ^ (row & 7)) * 8), Kl + i * 1024);
      } else {
        // V-tile [8 jg][256 c][16B]: slot (jg, cc) <- V[cc][j0 + jg*8 .. +7]
        const int jj = i - 32;
        const int jg = jj >> 2;
        const int cc = (jj & 3) * 64 + l;
        gload_lds16(Vb + (size_t)cc * HW + j0 + jg * 8, Vl + jg * 4096 + (jj & 3) * 1024);
      }
    }
  };

  const int j0base = js * 1024;
  const int NT = 16;   // 1024 / 64
  stage(0, j0base);
  asm volatile("s_waitcnt vmcnt(0)" ::: "memory");
  __builtin_amdgcn_s_barrier();

  for (int t = 0; t < NT; ++t) {
    const int cur = t & 1;
    if (t + 1 < NT) stage(cur ^ 1, j0base + (t + 1) * 64);
    const char* Kl = lds + cur * LBUF;
    const char* Vl = Kl + 32768;
#pragma unroll
    for (int h = 0; h < 2; ++h) {
      // ---- S^T half: j = h*32 + [0,32), this wave's 32 i-rows ----
      f32x4 sacc[2][2];   // [mjl][bi]
#pragma unroll
      for (int mjl = 0; mjl < 2; ++mjl)
#pragma unroll
        for (int bi = 0; bi < 2; ++bi)
#pragma unroll
          for (int r = 0; r < 4; ++r) sacc[mjl][bi][r] = 0.f;
      __builtin_amdgcn_s_setprio(1);
#pragma unroll
      for (int kc = 0; kc < 8; ++kc) {
        bf16x8 kf[2];
#pragma unroll
        for (int mjl = 0; mjl < 2; ++mjl) {
          const int row = h * 32 + mjl * 16 + base;
          const int c5 = (kc * 4 + g) ^ (row & 7);
          kf[mjl] = *(const bf16x8*)(Kl + row * 512 + c5 * 16);
        }
#pragma unroll
        for (int mjl = 0; mjl < 2; ++mjl)
#pragma unroll
          for (int bi = 0; bi < 2; ++bi)
            sacc[mjl][bi] = __builtin_amdgcn_mfma_f32_16x16x32_bf16(kf[mjl], q[bi][kc], sacc[mjl][bi], 0, 0, 0);
      }
      __builtin_amdgcn_s_setprio(0);
      // ---- exp + pack; lane holds P'[jloc = mjl*16+4g+r][i = iw0+bi*16+base] ----
#pragma unroll
      for (int bi = 0; bi < 2; ++bi) {
        const int iL = w * 32 + bi * 16 + base;
#pragma unroll
        for (int mjl = 0; mjl < 2; ++mjl) {
          const float p0 = __expf(sacc[mjl][bi][0] * 0.0625f - 8.0f);
          const float p1 = __expf(sacc[mjl][bi][1] * 0.0625f - 8.0f);
          const float p2 = __expf(sacc[mjl][bi][2] * 0.0625f - 8.0f);
          const float p3 = __expf(sacc[mjl][bi][3] * 0.0625f - 8.0f);
          const u16 e0 = f2bf(p0), e1 = f2bf(p1), e2 = f2bf(p2), e3 = f2bf(p3);
          rsum[bi] += (bf2f(e0) + bf2f(e1)) + (bf2f(e2) + bf2f(e3));
          P_block[iL][mjl * 8 + g * 2 + 0] = (unsigned)e0 | ((unsigned)e1 << 16);
          P_block[iL][mjl * 8 + g * 2 + 1] = (unsigned)e2 | ((unsigned)e3 << 16);
        }
      }
      asm volatile("s_waitcnt lgkmcnt(0)" ::: "memory");   // drain own P writes
      __builtin_amdgcn_sched_barrier(0);
      __builtin_amdgcn_s_barrier();                        // P_block visible to all waves
      // ---- PV: wave w computes O[all 256 i][w*32 .. w*32+32) over this 32-j chunk ----
      bf16x8 vf[2];
#pragma unroll
      for (int cf = 0; cf < 2; ++cf)
        vf[cf] = *(const bf16x8*)(Vl + (h * 4 + g) * 4096 + (w * 32 + cf * 16 + base) * 16);
      __builtin_amdgcn_s_setprio(1);
#pragma unroll
      for (int fi = 0; fi < 16; ++fi) {
        const bf16x8 af = *(const bf16x8*)&P_block[fi * 16 + base][g * 4];
#pragma unroll
        for (int cf = 0; cf < 2; ++cf)
          oacc[fi][cf] = __builtin_amdgcn_mfma_f32_16x16x32_bf16(af, vf[cf], oacc[fi][cf], 0, 0, 0);
      }
      __builtin_amdgcn_s_setprio(0);
      if (h == 0) {
        asm volatile("s_waitcnt lgkmcnt(0)" ::: "memory");  // PV reads done before h=1 pack overwrites
        __builtin_amdgcn_sched_barrier(0);
        __builtin_amdgcn_s_barrier();
      }
    }
    asm volatile("s_waitcnt vmcnt(0) lgkmcnt(0)" ::: "memory");  // staged tile ready; PV1 reads done
    __builtin_amdgcn_sched_barrier(0);
    __builtin_amdgcn_s_barrier();
  }

  // ---- epilogue: row-sum partials + O partials (f32) ----
  rsum[0] += __shfl_xor(rsum[0], 16); rsum[0] += __shfl_xor(rsum[0], 32);
  rsum[1] += __shfl_xor(rsum[1], 16); rsum[1] += __shfl_xor(rsum[1], 32);
  if (l < 16) {
    Rpart[(size_t)js * 16384 + b * HW + iw0 + 0 * 16 + l] = rsum[0];
    Rpart[(size_t)js * 16384 + b * HW + iw0 + 1 * 16 + l] = rsum[1];
  }
  float* Op = Opart + (size_t)js * 16384 * CCH + (size_t)b * HW * CCH + (size_t)it * 256 * CCH;
#pragma unroll
  for (int fi = 0; fi < 16; ++fi) {
#pragma unroll
    for (int cf = 0; cf < 2; ++cf) {
      const int c = w * 32 + cf * 16 + base;
#pragma unroll
      for (int r = 0; r < 4; ++r)
        Op[(size_t)(fi * 16 + g * 4 + r) * CCH + c] = oacc[fi][cf][r];
    }
  }
}

// ---------------- combine: Ot = bf16(sum_js O / sum_js r) ----------------
__global__ __launch_bounds__(256) void attn_combine(const float* __restrict__ Op,
                                                    const float* __restrict__ Rp,
                                                    u16* __restrict__ Ot) {
  const int idx = blockIdx.x * 256 + threadIdx.x;   // 1M threads
  const int row = idx >> 6;                         // b*4096 + i
  const int c4 = (idx & 63) * 4;
  float4 s = make_float4(0.f, 0.f, 0.f, 0.f);
  float rs = 0.f;
#pragma unroll
  for (int js = 0; js < 4; ++js) {
    const float4 o = *(const float4*)&Op[((size_t)js * 16384 + row) * CCH + c4];
    s.x += o.x; s.y += o.y; s.z += o.z; s.w += o.w;
    rs += Rp[(size_t)js * 16384 + row];
  }
  const float inv = 1.0f / rs;
  u16x4 r;
  r[0] = f2bf(s.x * inv);
  r[1] = f2bf(s.y * inv);
  r[2] = f2bf(s.z * inv);
  r[3] = f2bf(s.w * inv);
  *(u16x4*)&Ot[(size_t)row * CCH + c4] = r;
}

extern "C" void kernel_launch(void* const* d_in, const int* in_sizes, int n_in,
                              void* d_out, int out_size, void* d_ws, size_t ws_size,
                              hipStream_t stream) {
  const float* x   = (const float*)d_in[0];
  const float* gsc = (const float*)d_in[1];
  const float* gbi = (const float*)d_in[2];
  const float* wq  = (const float*)d_in[3];
  const float* bq  = (const float*)d_in[4];
  const float* wk  = (const float*)d_in[5];
  const float* bk  = (const float*)d_in[6];
  const float* wv  = (const float*)d_in[7];
  const float* bv  = (const float*)d_in[8];
  const float* wp  = (const float*)d_in[9];
  const float* bp  = (const float*)d_in[10];
  float* out = (float*)d_out;

  char* ws = (char*)d_ws;
  size_t off = 0;
  auto alloc = [&](size_t bytes) {
    size_t o = off; off = (off + bytes + 255) & ~(size_t)255; return o;
  };
  const size_t szMat = (size_t)NBATCH * HW * CCH * 2;   // 8.4MB
  u16* W      = (u16*)(ws + alloc(4 * 65536 * 2));
  float* pgn  = (float*)(ws + alloc(16 * 32 * 2 * 4));
  float2* st  = (float2*)(ws + alloc(16 * 8));
  u16* Ht = (u16*)(ws + alloc(szMat));   // [b][i][c]
  u16* Qt = (u16*)(ws + alloc(szMat));   // [b][i][c]
  u16* Kt = (u16*)(ws + alloc(szMat));   // [b][j][c]
  u16* Vv = (u16*)(ws + alloc(szMat));   // [b][c][j]
  u16* Ot = (u16*)(ws + alloc(szMat));   // [b][i][c]
  float* Opart = (float*)(ws + alloc((size_t)4 * 16384 * CCH * 4));  // 67MB
  float* Rpart = (float*)(ws + alloc((size_t)4 * 16384 * 4));        // 256KB

  const long sM = (long)HW * CCH;

  wcast<<<dim3(32, 4), 256, 0, stream>>>(wq, wk, wv, wp, W);
  gn_partial<<<dim3(32, 16), 256, 0, stream>>>(x, pgn);
  gn_finalize<<<1, 64, 0, stream>>>(pgn, st);
  norm_tr<<<dim3(HW / 64, CCH / 64, NBATCH), 256, 0, stream>>>(x, st, gsc, gbi, Ht);

  // fused QKV: A = [Wq;Wk;Wv] (768x256), B = Ht -> Qt [i][c], Kt [j][c], Vv [c][j]
  gemm2<5, true><<<dim3(32, 6, NBATCH), 256, 0, stream>>>(
      W, 256, 0, Ht, 256, sM, Qt, 256, sM, Kt, Vv, bq, bk, bv, nullptr, 0, 1.f, 256);

  // fused attention
  attn_fused<<<256, 512, 0, stream>>>(Qt, Kt, Vv, Opart, Rpart);
  attn_combine<<<4096, 256, 0, stream>>>(Opart, Rpart, Ot);

  // out[c][i] = Wp . Ot^T + bp + x
  gemm2<2, true><<<dim3(32, 2, NBATCH), 256, 0, stream>>>(
      W + 3 * 65536, 256, 0, Ot, 256, sM, out, HW, (long)CCH * HW, nullptr, nullptr,
      bp, nullptr, nullptr, x, (long)CCH * HW, 1.f, 256);
}

// Round 9
// 316.652 us; speedup vs baseline: 1.0036x; 1.0019x over previous
//
#include <hip/hip_runtime.h>

// AttnBlock: GroupNorm(4) -> fused qkv 1x1conv -> FUSED flash attention
//            (S^T via mfma(K,Q), exp(s/16-8), block-level P_block relayout, PV
//             with per-wave 32-channel output slice) -> combine -> proj + residual
// bf16 MFMA 16x16x32, fp32 accumulate.
// REGISTER-CAP HEDGE: hipcc caps 512-thread kernels at 128 VGPR under every
// launch_bounds/waves_per_eu combo tried (r6-r8 -> 128-reg spill, 467MB scratch).
// attn_fused<NBI>: NBI=2 (256-i tile, needs ~200 regs) / NBI=1 (128-i, fits ~128).
// Host queries hipFuncGetAttributes(numRegs) of <2> and dispatches accordingly.

#define HW 4096
#define CCH 256
#define NBATCH 4
#define GN_N (64 * HW)

typedef unsigned short u16;
typedef __attribute__((ext_vector_type(8))) short bf16x8;
typedef __attribute__((ext_vector_type(4))) float f32x4;
typedef __attribute__((ext_vector_type(4))) u16 u16x4;

__device__ __forceinline__ u16 f2bf(float f) {
  unsigned u = __float_as_uint(f);
  u += 0x7fffu + ((u >> 16) & 1u);   // round-to-nearest-even
  return (u16)(u >> 16);
}
__device__ __forceinline__ float bf2f(u16 h) { return __uint_as_float(((unsigned)h) << 16); }

__device__ __forceinline__ void gload_lds16(const void* g, void* l) {
  __builtin_amdgcn_global_load_lds(
      (const __attribute__((address_space(1))) unsigned*)g,
      (__attribute__((address_space(3))) unsigned*)l, 16, 0, 0);
}

// ---------------- GroupNorm stats ----------------
__global__ __launch_bounds__(256) void gn_partial(const float* __restrict__ x,
                                                  float* __restrict__ part) {
  const int bg = blockIdx.y, blk = blockIdx.x, tid = threadIdx.x;
  const float4* X = (const float4*)(x + (size_t)bg * GN_N);
  float s = 0.f, ss = 0.f;
#pragma unroll
  for (int u = 0; u < 8; ++u) {
    float4 v = X[blk * 2048 + u * 256 + tid];
    s += v.x + v.y + v.z + v.w;
    ss += v.x * v.x + v.y * v.y + v.z * v.z + v.w * v.w;
  }
  for (int off = 32; off; off >>= 1) { s += __shfl_xor(s, off); ss += __shfl_xor(ss, off); }
  __shared__ float rs[4], rss[4];
  const int w = tid >> 6;
  if ((tid & 63) == 0) { rs[w] = s; rss[w] = ss; }
  __syncthreads();
  if (tid == 0) {
    part[(bg * 32 + blk) * 2 + 0] = rs[0] + rs[1] + rs[2] + rs[3];
    part[(bg * 32 + blk) * 2 + 1] = rss[0] + rss[1] + rss[2] + rss[3];
  }
}

__global__ void gn_finalize(const float* __restrict__ part, float2* __restrict__ stats) {
  const int t = threadIdx.x;
  if (t < 16) {
    float s = 0.f, ss = 0.f;
    for (int u = 0; u < 32; ++u) { s += part[(t * 32 + u) * 2]; ss += part[(t * 32 + u) * 2 + 1]; }
    const float mean = s * (1.0f / GN_N);
    const float var = ss * (1.0f / GN_N) - mean * mean;
    stats[t] = make_float2(mean, rsqrtf(var + 1e-6f));
  }
}

// ---------------- normalize + transpose -> Ht[b][i][c] bf16 ----------------
__global__ __launch_bounds__(256) void norm_tr(const float* __restrict__ x,
                                               const float2* __restrict__ stats,
                                               const float* __restrict__ gsc,
                                               const float* __restrict__ gbi,
                                               u16* __restrict__ Ht) {
  __shared__ u16 T[64][72];
  const int i0 = blockIdx.x * 64, c0 = blockIdx.y * 64, b = blockIdx.z;
  const int tid = threadIdx.x;
  const int cl = tid >> 4;
  const int il4 = (tid & 15) * 4;
#pragma unroll
  for (int it = 0; it < 4; ++it) {
    const int c = c0 + it * 16 + cl;
    const float2 st = stats[b * 4 + (c >> 6)];
    const float sc = gsc[c] * st.y;
    const float bi = gbi[c] - st.x * sc;
    const float4 v = *(const float4*)&x[((size_t)(b * CCH + c)) * HW + i0 + il4];
    T[il4 + 0][it * 16 + cl] = f2bf(v.x * sc + bi);
    T[il4 + 1][it * 16 + cl] = f2bf(v.y * sc + bi);
    T[il4 + 2][it * 16 + cl] = f2bf(v.z * sc + bi);
    T[il4 + 3][it * 16 + cl] = f2bf(v.w * sc + bi);
  }
  __syncthreads();
  const int il = tid >> 2, cs = (tid & 3) * 16;
  const uint4 a = *(const uint4*)&T[il][cs];
  const uint4 b2 = *(const uint4*)&T[il][cs + 8];
  const size_t o = ((size_t)b * HW + i0 + il) * CCH + c0 + cs;
  *(uint4*)&Ht[o] = a;
  *(uint4*)&Ht[o + 8] = b2;
}

// ---------------- cast weights fp32 -> bf16 ----------------
__global__ __launch_bounds__(256) void wcast(const float* __restrict__ w0, const float* __restrict__ w1,
                                             const float* __restrict__ w2, const float* __restrict__ w3,
                                             u16* __restrict__ dst) {
  const float* src = blockIdx.y == 0 ? w0 : blockIdx.y == 1 ? w1 : blockIdx.y == 2 ? w2 : w3;
  u16* d = dst + (size_t)blockIdx.y * 65536;
  const int idx = (blockIdx.x * 256 + threadIdx.x) * 8;
  const float4 a = *(const float4*)&src[idx];
  const float4 c = *(const float4*)&src[idx + 4];
  uint4 p;
  p.x = (unsigned)f2bf(a.x) | ((unsigned)f2bf(a.y) << 16);
  p.y = (unsigned)f2bf(a.z) | ((unsigned)f2bf(a.w) << 16);
  p.z = (unsigned)f2bf(c.x) | ((unsigned)f2bf(c.y) << 16);
  p.w = (unsigned)f2bf(c.z) | ((unsigned)f2bf(c.w) << 16);
  *(uint4*)&d[idx] = p;
}

// ---------------- NT GEMM (QKV + proj), 2-phase dbuf, as validated ----------------
template <int EPI, bool HASB>
__global__ __launch_bounds__(256) void gemm2(
    const u16* __restrict__ A, int lda, long sA,
    const u16* __restrict__ Bm, int ldb, long sB,
    void* __restrict__ O0, int ldo, long sO,
    void* __restrict__ O1, void* __restrict__ O2,
    const float* __restrict__ b0, const float* __restrict__ b1, const float* __restrict__ b2,
    const float* __restrict__ aux, long sAux,
    float scale, int K) {
  __shared__ char lsA[32768], lsB[32768];
  int bx, by, bz;
  {
    const int nx = gridDim.x, ny = gridDim.y;
    const int lin = blockIdx.x + nx * (blockIdx.y + ny * blockIdx.z);
    const int q = (nx * ny * (int)gridDim.z) >> 3;
    const int wg = (lin & 7) * q + (lin >> 3);
    bx = wg % nx; const int t2 = wg / nx; by = t2 % ny; bz = t2 / ny;
  }
  const int tid = threadIdx.x;
  const int w = tid >> 6, l = tid & 63;
  const int wm = w >> 1, wn = w & 1;
  const int m0 = by * 128, n0 = bx * 128;
  const u16* Ab = A + (size_t)bz * sA;
  const u16* Bb = Bm + (size_t)bz * sB;

  f32x4 acc[4][4];
#pragma unroll
  for (int i = 0; i < 4; ++i)
#pragma unroll
    for (int j = 0; j < 4; ++j)
#pragma unroll
      for (int q2 = 0; q2 < 4; ++q2) acc[i][j][q2] = 0.f;

  auto stage = [&](int buf, int k0) {
#pragma unroll
    for (int s = 0; s < 4; ++s) {
      const int o = s * 4096 + tid * 16;
      const int r = o >> 7;
      const int c = ((o >> 4) & 7) ^ (r & 7);
      const int ke = c * 8;
      gload_lds16(Ab + (size_t)(m0 + r) * lda + k0 + ke, lsA + buf * 16384 + s * 4096 + w * 1024);
      gload_lds16(Bb + (size_t)(n0 + r) * ldb + k0 + ke, lsB + buf * 16384 + s * 4096 + w * 1024);
    }
  };

  const int nt = K >> 6;
  stage(0, 0);
  asm volatile("s_waitcnt vmcnt(0)" ::: "memory");
  __syncthreads();
  for (int t = 0; t < nt; ++t) {
    const int cur = t & 1;
    if (t + 1 < nt) stage(cur ^ 1, (t + 1) << 6);
#pragma unroll
    for (int kk = 0; kk < 2; ++kk) {
      bf16x8 aF[4], bF[4];
#pragma unroll
      for (int mi = 0; mi < 4; ++mi) {
        const int r = wm * 64 + mi * 16 + (l & 15);
        const int cc = (kk * 4 + (l >> 4)) ^ (r & 7);
        aF[mi] = *(const bf16x8*)(lsA + cur * 16384 + r * 128 + cc * 16);
      }
#pragma unroll
      for (int ni = 0; ni < 4; ++ni) {
        const int r = wn * 64 + ni * 16 + (l & 15);
        const int cc = (kk * 4 + (l >> 4)) ^ (r & 7);
        bF[ni] = *(const bf16x8*)(lsB + cur * 16384 + r * 128 + cc * 16);
      }
#pragma unroll
      for (int mi = 0; mi < 4; ++mi)
#pragma unroll
        for (int ni = 0; ni < 4; ++ni)
          acc[mi][ni] = __builtin_amdgcn_mfma_f32_16x16x32_bf16(aF[mi], bF[ni], acc[mi][ni], 0, 0, 0);
    }
    asm volatile("s_waitcnt vmcnt(0)" ::: "memory");
    __syncthreads();
  }

  const int lc = l & 15;
  const int lr4 = (l >> 4) * 4;   // C/D: col=lane&15, row=(lane>>4)*4+reg

  if (EPI == 5) {
    const int sel = m0 >> 8;   // 0:Q 1:K 2:V
    const float* bs = sel == 0 ? b0 : sel == 1 ? b1 : b2;
#pragma unroll
    for (int mi = 0; mi < 4; ++mi) {
      const int mg = m0 + wm * 64 + mi * 16 + lr4;
      const int mloc = mg & 255;
      const float4 bv = *(const float4*)&bs[mloc];
      float bb4[4] = {bv.x, bv.y, bv.z, bv.w};
#pragma unroll
      for (int ni = 0; ni < 4; ++ni) {
        const int n = n0 + wn * 64 + ni * 16 + lc;
        if (sel == 2) {
          u16* V = (u16*)O2 + (size_t)bz * sO;
#pragma unroll
          for (int q2 = 0; q2 < 4; ++q2) V[(size_t)(mloc + q2) * HW + n] = f2bf(acc[mi][ni][q2] + bb4[q2]);
        } else {
          u16* Oq = (u16*)(sel == 0 ? O0 : O1) + (size_t)bz * sO;
          u16x4 pk;
#pragma unroll
          for (int q2 = 0; q2 < 4; ++q2) pk[q2] = f2bf(acc[mi][ni][q2] + bb4[q2]);
          *(u16x4*)&Oq[(size_t)n * CCH + mloc] = pk;
        }
      }
    }
  } else {   // EPI == 2: fp32 out + bias + residual
    float* O = (float*)O0 + (size_t)bz * sO;
    const float* R = aux + (size_t)bz * sAux;
#pragma unroll
    for (int mi = 0; mi < 4; ++mi) {
      const int mb = m0 + wm * 64 + mi * 16 + lr4;
      float bb4[4] = {0.f, 0.f, 0.f, 0.f};
      if (HASB) {
        const float4 bv = *(const float4*)&b0[mb];
        bb4[0] = bv.x; bb4[1] = bv.y; bb4[2] = bv.z; bb4[3] = bv.w;
      }
#pragma unroll
      for (int ni = 0; ni < 4; ++ni) {
        const int n = n0 + wn * 64 + ni * 16 + lc;
#pragma unroll
        for (int q2 = 0; q2 < 4; ++q2)
          O[(size_t)(mb + q2) * ldo + n] = acc[mi][ni][q2] * scale + bb4[q2] + R[(size_t)(mb + q2) * ldo + n];
      }
    }
  }
}

// ---------------- fused flash attention (template on i-tile size) ----------------
// Grid: (HW/ITILE)*16 blocks x 512 thr (8 waves). it=bid>>4, b=(bid>>2)&3, js=bid&3.
// ITILE = 128*NBI i-rows per block; each wave owns 16*NBI i-rows for S phase.
// Per t (KVBLK=64 j), two 32-j halves:
//   S^T = mfma(K, Q) -> exp(s/16-8) -> pack to P_block[ITILE][32 j]
//   -> barrier -> PV: wave w owns channels [w*32, w*32+32) for ALL ITILE rows.
#define LBUF 65536            // K 32KB | V 32KB per buffer
template <int NBI>
__global__ __launch_bounds__(512) void attn_fused(
    const u16* __restrict__ Qt, const u16* __restrict__ Kt, const u16* __restrict__ Vv,
    float* __restrict__ Opart, float* __restrict__ Rpart) {
  constexpr int ITILE = 128 * NBI;
  __shared__ __attribute__((aligned(16))) char lds[2 * LBUF];
  __shared__ __attribute__((aligned(16))) unsigned P_block[ITILE][20];  // stride 20 dw
  const int bid = blockIdx.x;
  const int it = bid >> 4, b = (bid >> 2) & 3, js = bid & 3;
  const int tid = threadIdx.x, w = tid >> 6, l = tid & 63;
  const int g = l >> 4, base = l & 15;
  const u16* Qb = Qt + (size_t)b * HW * CCH;
  const u16* Kb = Kt + (size_t)b * HW * CCH;
  const u16* Vb = Vv + (size_t)b * CCH * HW;
  const int iw0 = it * ITILE + w * 16 * NBI;

  bf16x8 q[NBI][8];
#pragma unroll
  for (int bi = 0; bi < NBI; ++bi)
#pragma unroll
    for (int kc = 0; kc < 8; ++kc)
      q[bi][kc] = *(const bf16x8*)&Qb[(size_t)(iw0 + bi * 16 + base) * CCH + kc * 32 + g * 8];

  f32x4 oacc[8 * NBI][2];   // O[it*ITILE + fi*16 + g*4 + r][w*32 + cf*16 + base]
#pragma unroll
  for (int fi = 0; fi < 8 * NBI; ++fi)
#pragma unroll
    for (int cf = 0; cf < 2; ++cf)
#pragma unroll
      for (int r = 0; r < 4; ++r) oacc[fi][cf][r] = 0.f;
  float rsum[NBI];
#pragma unroll
  for (int bi = 0; bi < NBI; ++bi) rsum[bi] = 0.f;

  auto stage = [&](int buf, int j0) {
    char* Kl = lds + buf * LBUF;
    char* Vl = Kl + 32768;
#pragma unroll
    for (int s = 0; s < 8; ++s) {
      const int i = w * 8 + s;   // 0..63 (wave-uniform)
      if (i < 32) {
        const int row = i * 2 + (l >> 5);
        const int c5 = l & 31;
        gload_lds16(Kb + (size_t)(j0 + row) * CCH + ((c5 ^ (row & 7)) * 8), Kl + i * 1024);
      } else {
        const int jj = i - 32;
        const int jg = jj >> 2;
        const int cc = (jj & 3) * 64 + l;
        gload_lds16(Vb + (size_t)cc * HW + j0 + jg * 8, Vl + jg * 4096 + (jj & 3) * 1024);
      }
    }
  };

  const int j0base = js * 1024;
  const int NT = 16;   // 1024 / 64
  stage(0, j0base);
  asm volatile("s_waitcnt vmcnt(0)" ::: "memory");
  __builtin_amdgcn_s_barrier();

  for (int t = 0; t < NT; ++t) {
    const int cur = t & 1;
    if (t + 1 < NT) stage(cur ^ 1, j0base + (t + 1) * 64);
    const char* Kl = lds + cur * LBUF;
    const char* Vl = Kl + 32768;
#pragma unroll
    for (int h = 0; h < 2; ++h) {
      // ---- S^T half: j = h*32 + [0,32), this wave's 16*NBI i-rows ----
      f32x4 sacc[2][NBI];
#pragma unroll
      for (int mjl = 0; mjl < 2; ++mjl)
#pragma unroll
        for (int bi = 0; bi < NBI; ++bi)
#pragma unroll
          for (int r = 0; r < 4; ++r) sacc[mjl][bi][r] = 0.f;
      __builtin_amdgcn_s_setprio(1);
#pragma unroll
      for (int kc = 0; kc < 8; ++kc) {
        bf16x8 kf[2];
#pragma unroll
        for (int mjl = 0; mjl < 2; ++mjl) {
          const int row = h * 32 + mjl * 16 + base;
          const int c5 = (kc * 4 + g) ^ (row & 7);
          kf[mjl] = *(const bf16x8*)(Kl + row * 512 + c5 * 16);
        }
#pragma unroll
        for (int mjl = 0; mjl < 2; ++mjl)
#pragma unroll
          for (int bi = 0; bi < NBI; ++bi)
            sacc[mjl][bi] = __builtin_amdgcn_mfma_f32_16x16x32_bf16(kf[mjl], q[bi][kc], sacc[mjl][bi], 0, 0, 0);
      }
      __builtin_amdgcn_s_setprio(0);
      // ---- exp + pack; lane holds P'[jloc = mjl*16+4g+r][i-row bi*16+base] ----
#pragma unroll
      for (int bi = 0; bi < NBI; ++bi) {
        const int iL = w * 16 * NBI + bi * 16 + base;
#pragma unroll
        for (int mjl = 0; mjl < 2; ++mjl) {
          const float p0 = __expf(sacc[mjl][bi][0] * 0.0625f - 8.0f);
          const float p1 = __expf(sacc[mjl][bi][1] * 0.0625f - 8.0f);
          const float p2 = __expf(sacc[mjl][bi][2] * 0.0625f - 8.0f);
          const float p3 = __expf(sacc[mjl][bi][3] * 0.0625f - 8.0f);
          const u16 e0 = f2bf(p0), e1 = f2bf(p1), e2 = f2bf(p2), e3 = f2bf(p3);
          rsum[bi] += (bf2f(e0) + bf2f(e1)) + (bf2f(e2) + bf2f(e3));
          P_block[iL][mjl * 8 + g * 2 + 0] = (unsigned)e0 | ((unsigned)e1 << 16);
          P_block[iL][mjl * 8 + g * 2 + 1] = (unsigned)e2 | ((unsigned)e3 << 16);
        }
      }
      asm volatile("s_waitcnt lgkmcnt(0)" ::: "memory");
      __builtin_amdgcn_sched_barrier(0);
      __builtin_amdgcn_s_barrier();
      // ---- PV: wave w computes O[all ITILE i][w*32 .. +32) over this 32-j chunk ----
      bf16x8 vf[2];
#pragma unroll
      for (int cf = 0; cf < 2; ++cf)
        vf[cf] = *(const bf16x8*)(Vl + (h * 4 + g) * 4096 + (w * 32 + cf * 16 + base) * 16);
      __builtin_amdgcn_s_setprio(1);
#pragma unroll
      for (int fi = 0; fi < 8 * NBI; ++fi) {
        const bf16x8 af = *(const bf16x8*)&P_block[fi * 16 + base][g * 4];
#pragma unroll
        for (int cf = 0; cf < 2; ++cf)
          oacc[fi][cf] = __builtin_amdgcn_mfma_f32_16x16x32_bf16(af, vf[cf], oacc[fi][cf], 0, 0, 0);
      }
      __builtin_amdgcn_s_setprio(0);
      if (h == 0) {
        asm volatile("s_waitcnt lgkmcnt(0)" ::: "memory");
        __builtin_amdgcn_sched_barrier(0);
        __builtin_amdgcn_s_barrier();
      }
    }
    asm volatile("s_waitcnt vmcnt(0) lgkmcnt(0)" ::: "memory");
    __builtin_amdgcn_sched_barrier(0);
    __builtin_amdgcn_s_barrier();
  }

  // ---- epilogue ----
#pragma unroll
  for (int bi = 0; bi < NBI; ++bi) {
    rsum[bi] += __shfl_xor(rsum[bi], 16);
    rsum[bi] += __shfl_xor(rsum[bi], 32);
    if (l < 16) Rpart[(size_t)js * 16384 + b * HW + iw0 + bi * 16 + l] = rsum[bi];
  }
  float* Op = Opart + (size_t)js * 16384 * CCH + (size_t)b * HW * CCH + (size_t)it * ITILE * CCH;
#pragma unroll
  for (int fi = 0; fi < 8 * NBI; ++fi) {
#pragma unroll
    for (int cf = 0; cf < 2; ++cf) {
      const int c = w * 32 + cf * 16 + base;
#pragma unroll
      for (int r = 0; r < 4; ++r)
        Op[(size_t)(fi * 16 + g * 4 + r) * CCH + c] = oacc[fi][cf][r];
    }
  }
}

// ---------------- combine: Ot = bf16(sum_js O / sum_js r) ----------------
__global__ __launch_bounds__(256) void attn_combine(const float* __restrict__ Op,
                                                    const float* __restrict__ Rp,
                                                    u16* __restrict__ Ot) {
  const int idx = blockIdx.x * 256 + threadIdx.x;
  const int row = idx >> 6;
  const int c4 = (idx & 63) * 4;
  float4 s = make_float4(0.f, 0.f, 0.f, 0.f);
  float rs = 0.f;
#pragma unroll
  for (int js = 0; js < 4; ++js) {
    const float4 o = *(const float4*)&Op[((size_t)js * 16384 + row) * CCH + c4];
    s.x += o.x; s.y += o.y; s.z += o.z; s.w += o.w;
    rs += Rp[(size_t)js * 16384 + row];
  }
  const float inv = 1.0f / rs;
  u16x4 r;
  r[0] = f2bf(s.x * inv);
  r[1] = f2bf(s.y * inv);
  r[2] = f2bf(s.z * inv);
  r[3] = f2bf(s.w * inv);
  *(u16x4*)&Ot[(size_t)row * CCH + c4] = r;
}

extern "C" void kernel_launch(void* const* d_in, const int* in_sizes, int n_in,
                              void* d_out, int out_size, void* d_ws, size_t ws_size,
                              hipStream_t stream) {
  const float* x   = (const float*)d_in[0];
  const float* gsc = (const float*)d_in[1];
  const float* gbi = (const float*)d_in[2];
  const float* wq  = (const float*)d_in[3];
  const float* bq  = (const float*)d_in[4];
  const float* wk  = (const float*)d_in[5];
  const float* bk  = (const float*)d_in[6];
  const float* wv  = (const float*)d_in[7];
  const float* bv  = (const float*)d_in[8];
  const float* wp  = (const float*)d_in[9];
  const float* bp  = (const float*)d_in[10];
  float* out = (float*)d_out;

  char* ws = (char*)d_ws;
  size_t off = 0;
  auto alloc = [&](size_t bytes) {
    size_t o = off; off = (off + bytes + 255) & ~(size_t)255; return o;
  };
  const size_t szMat = (size_t)NBATCH * HW * CCH * 2;
  u16* W      = (u16*)(ws + alloc(4 * 65536 * 2));
  float* pgn  = (float*)(ws + alloc(16 * 32 * 2 * 4));
  float2* st  = (float2*)(ws + alloc(16 * 8));
  u16* Ht = (u16*)(ws + alloc(szMat));
  u16* Qt = (u16*)(ws + alloc(szMat));
  u16* Kt = (u16*)(ws + alloc(szMat));
  u16* Vv = (u16*)(ws + alloc(szMat));
  u16* Ot = (u16*)(ws + alloc(szMat));
  float* Opart = (float*)(ws + alloc((size_t)4 * 16384 * CCH * 4));  // 67MB
  float* Rpart = (float*)(ws + alloc((size_t)4 * 16384 * 4));

  const long sM = (long)HW * CCH;

  wcast<<<dim3(32, 4), 256, 0, stream>>>(wq, wk, wv, wp, W);
  gn_partial<<<dim3(32, 16), 256, 0, stream>>>(x, pgn);
  gn_finalize<<<1, 64, 0, stream>>>(pgn, st);
  norm_tr<<<dim3(HW / 64, CCH / 64, NBATCH), 256, 0, stream>>>(x, st, gsc, gbi, Ht);

  gemm2<5, true><<<dim3(32, 6, NBATCH), 256, 0, stream>>>(
      W, 256, 0, Ht, 256, sM, Qt, 256, sM, Kt, Vv, bq, bk, bv, nullptr, 0, 1.f, 256);

  // dispatch attn variant by compiled register count of the big tile
  hipFuncAttributes fa{};
  (void)hipFuncGetAttributes(&fa, (const void*)attn_fused<2>);
  if (fa.numRegs >= 160) {
    attn_fused<2><<<256, 512, 0, stream>>>(Qt, Kt, Vv, Opart, Rpart);
  } else {
    attn_fused<1><<<512, 512, 0, stream>>>(Qt, Kt, Vv, Opart, Rpart);
  }
  attn_combine<<<4096, 256, 0, stream>>>(Opart, Rpart, Ot);

  gemm2<2, true><<<dim3(32, 2, NBATCH), 256, 0, stream>>>(
      W + 3 * 65536, 256, 0, Ot, 256, sM, out, HW, (long)CCH * HW, nullptr, nullptr,
      bp, nullptr, nullptr, x, (long)CCH * HW, 1.f, 256);
}

// Round 10
// 187.694 us; speedup vs baseline: 1.6932x; 1.6871x over previous
//
#include <hip/hip_runtime.h>

// AttnBlock: GroupNorm(4) -> fused qkv 1x1conv -> FUSED flash attention
//            -> combine (2-way jh merge + 1/l) -> proj 1x1conv + residual
// bf16 MFMA 16x16x32, fp32 accumulate.
// attn_fused: 256 threads (4 waves) — the ONE config this toolchain gives >128
// VGPRs (round-4 evidence: 200). ITILE=64, KVBLK=32, ~69KB LDS -> 2 blocks/CU.

#define HW 4096
#define CCH 256
#define NBATCH 4
#define GN_N (64 * HW)

typedef unsigned short u16;
typedef __attribute__((ext_vector_type(8))) short bf16x8;
typedef __attribute__((ext_vector_type(4))) float f32x4;
typedef __attribute__((ext_vector_type(4))) u16 u16x4;

__device__ __forceinline__ u16 f2bf(float f) {
  unsigned u = __float_as_uint(f);
  u += 0x7fffu + ((u >> 16) & 1u);   // round-to-nearest-even
  return (u16)(u >> 16);
}
__device__ __forceinline__ float bf2f(u16 h) { return __uint_as_float(((unsigned)h) << 16); }

__device__ __forceinline__ void gload_lds16(const void* g, void* l) {
  __builtin_amdgcn_global_load_lds(
      (const __attribute__((address_space(1))) unsigned*)g,
      (__attribute__((address_space(3))) unsigned*)l, 16, 0, 0);
}

// ---------------- GroupNorm stats ----------------
__global__ __launch_bounds__(256) void gn_partial(const float* __restrict__ x,
                                                  float* __restrict__ part) {
  const int bg = blockIdx.y, blk = blockIdx.x, tid = threadIdx.x;
  const float4* X = (const float4*)(x + (size_t)bg * GN_N);
  float s = 0.f, ss = 0.f;
#pragma unroll
  for (int u = 0; u < 8; ++u) {
    float4 v = X[blk * 2048 + u * 256 + tid];
    s += v.x + v.y + v.z + v.w;
    ss += v.x * v.x + v.y * v.y + v.z * v.z + v.w * v.w;
  }
  for (int off = 32; off; off >>= 1) { s += __shfl_xor(s, off); ss += __shfl_xor(ss, off); }
  __shared__ float rs[4], rss[4];
  const int w = tid >> 6;
  if ((tid & 63) == 0) { rs[w] = s; rss[w] = ss; }
  __syncthreads();
  if (tid == 0) {
    part[(bg * 32 + blk) * 2 + 0] = rs[0] + rs[1] + rs[2] + rs[3];
    part[(bg * 32 + blk) * 2 + 1] = rss[0] + rss[1] + rss[2] + rss[3];
  }
}

__global__ void gn_finalize(const float* __restrict__ part, float2* __restrict__ stats) {
  const int t = threadIdx.x;
  if (t < 16) {
    float s = 0.f, ss = 0.f;
    for (int u = 0; u < 32; ++u) { s += part[(t * 32 + u) * 2]; ss += part[(t * 32 + u) * 2 + 1]; }
    const float mean = s * (1.0f / GN_N);
    const float var = ss * (1.0f / GN_N) - mean * mean;
    stats[t] = make_float2(mean, rsqrtf(var + 1e-6f));
  }
}

// ---------------- normalize + transpose -> Ht[b][i][c] bf16 ----------------
__global__ __launch_bounds__(256) void norm_tr(const float* __restrict__ x,
                                               const float2* __restrict__ stats,
                                               const float* __restrict__ gsc,
                                               const float* __restrict__ gbi,
                                               u16* __restrict__ Ht) {
  __shared__ u16 T[64][72];
  const int i0 = blockIdx.x * 64, c0 = blockIdx.y * 64, b = blockIdx.z;
  const int tid = threadIdx.x;
  const int cl = tid >> 4;
  const int il4 = (tid & 15) * 4;
#pragma unroll
  for (int it = 0; it < 4; ++it) {
    const int c = c0 + it * 16 + cl;
    const float2 st = stats[b * 4 + (c >> 6)];
    const float sc = gsc[c] * st.y;
    const float bi = gbi[c] - st.x * sc;
    const float4 v = *(const float4*)&x[((size_t)(b * CCH + c)) * HW + i0 + il4];
    T[il4 + 0][it * 16 + cl] = f2bf(v.x * sc + bi);
    T[il4 + 1][it * 16 + cl] = f2bf(v.y * sc + bi);
    T[il4 + 2][it * 16 + cl] = f2bf(v.z * sc + bi);
    T[il4 + 3][it * 16 + cl] = f2bf(v.w * sc + bi);
  }
  __syncthreads();
  const int il = tid >> 2, cs = (tid & 3) * 16;
  const uint4 a = *(const uint4*)&T[il][cs];
  const uint4 b2 = *(const uint4*)&T[il][cs + 8];
  const size_t o = ((size_t)b * HW + i0 + il) * CCH + c0 + cs;
  *(uint4*)&Ht[o] = a;
  *(uint4*)&Ht[o + 8] = b2;
}

// ---------------- cast weights fp32 -> bf16 ----------------
__global__ __launch_bounds__(256) void wcast(const float* __restrict__ w0, const float* __restrict__ w1,
                                             const float* __restrict__ w2, const float* __restrict__ w3,
                                             u16* __restrict__ dst) {
  const float* src = blockIdx.y == 0 ? w0 : blockIdx.y == 1 ? w1 : blockIdx.y == 2 ? w2 : w3;
  u16* d = dst + (size_t)blockIdx.y * 65536;
  const int idx = (blockIdx.x * 256 + threadIdx.x) * 8;
  const float4 a = *(const float4*)&src[idx];
  const float4 c = *(const float4*)&src[idx + 4];
  uint4 p;
  p.x = (unsigned)f2bf(a.x) | ((unsigned)f2bf(a.y) << 16);
  p.y = (unsigned)f2bf(a.z) | ((unsigned)f2bf(a.w) << 16);
  p.z = (unsigned)f2bf(c.x) | ((unsigned)f2bf(c.y) << 16);
  p.w = (unsigned)f2bf(c.z) | ((unsigned)f2bf(c.w) << 16);
  *(uint4*)&d[idx] = p;
}

// ---------------- NT GEMM (QKV + proj), 2-phase dbuf, as validated ----------------
template <int EPI, bool HASB>
__global__ __launch_bounds__(256) void gemm2(
    const u16* __restrict__ A, int lda, long sA,
    const u16* __restrict__ Bm, int ldb, long sB,
    void* __restrict__ O0, int ldo, long sO,
    void* __restrict__ O1, void* __restrict__ O2,
    const float* __restrict__ b0, const float* __restrict__ b1, const float* __restrict__ b2,
    const float* __restrict__ aux, long sAux,
    float scale, int K) {
  __shared__ char lsA[32768], lsB[32768];
  int bx, by, bz;
  {
    const int nx = gridDim.x, ny = gridDim.y;
    const int lin = blockIdx.x + nx * (blockIdx.y + ny * blockIdx.z);
    const int q = (nx * ny * (int)gridDim.z) >> 3;
    const int wg = (lin & 7) * q + (lin >> 3);
    bx = wg % nx; const int t2 = wg / nx; by = t2 % ny; bz = t2 / ny;
  }
  const int tid = threadIdx.x;
  const int w = tid >> 6, l = tid & 63;
  const int wm = w >> 1, wn = w & 1;
  const int m0 = by * 128, n0 = bx * 128;
  const u16* Ab = A + (size_t)bz * sA;
  const u16* Bb = Bm + (size_t)bz * sB;

  f32x4 acc[4][4];
#pragma unroll
  for (int i = 0; i < 4; ++i)
#pragma unroll
    for (int j = 0; j < 4; ++j)
#pragma unroll
      for (int q2 = 0; q2 < 4; ++q2) acc[i][j][q2] = 0.f;

  auto stage = [&](int buf, int k0) {
#pragma unroll
    for (int s = 0; s < 4; ++s) {
      const int o = s * 4096 + tid * 16;
      const int r = o >> 7;
      const int c = ((o >> 4) & 7) ^ (r & 7);
      const int ke = c * 8;
      gload_lds16(Ab + (size_t)(m0 + r) * lda + k0 + ke, lsA + buf * 16384 + s * 4096 + w * 1024);
      gload_lds16(Bb + (size_t)(n0 + r) * ldb + k0 + ke, lsB + buf * 16384 + s * 4096 + w * 1024);
    }
  };

  const int nt = K >> 6;
  stage(0, 0);
  asm volatile("s_waitcnt vmcnt(0)" ::: "memory");
  __syncthreads();
  for (int t = 0; t < nt; ++t) {
    const int cur = t & 1;
    if (t + 1 < nt) stage(cur ^ 1, (t + 1) << 6);
#pragma unroll
    for (int kk = 0; kk < 2; ++kk) {
      bf16x8 aF[4], bF[4];
#pragma unroll
      for (int mi = 0; mi < 4; ++mi) {
        const int r = wm * 64 + mi * 16 + (l & 15);
        const int cc = (kk * 4 + (l >> 4)) ^ (r & 7);
        aF[mi] = *(const bf16x8*)(lsA + cur * 16384 + r * 128 + cc * 16);
      }
#pragma unroll
      for (int ni = 0; ni < 4; ++ni) {
        const int r = wn * 64 + ni * 16 + (l & 15);
        const int cc = (kk * 4 + (l >> 4)) ^ (r & 7);
        bF[ni] = *(const bf16x8*)(lsB + cur * 16384 + r * 128 + cc * 16);
      }
#pragma unroll
      for (int mi = 0; mi < 4; ++mi)
#pragma unroll
        for (int ni = 0; ni < 4; ++ni)
          acc[mi][ni] = __builtin_amdgcn_mfma_f32_16x16x32_bf16(aF[mi], bF[ni], acc[mi][ni], 0, 0, 0);
    }
    asm volatile("s_waitcnt vmcnt(0)" ::: "memory");
    __syncthreads();
  }

  const int lc = l & 15;
  const int lr4 = (l >> 4) * 4;   // C/D: col=lane&15, row=(lane>>4)*4+reg

  if (EPI == 5) {
    const int sel = m0 >> 8;   // 0:Q 1:K 2:V
    const float* bs = sel == 0 ? b0 : sel == 1 ? b1 : b2;
#pragma unroll
    for (int mi = 0; mi < 4; ++mi) {
      const int mg = m0 + wm * 64 + mi * 16 + lr4;
      const int mloc = mg & 255;
      const float4 bv = *(const float4*)&bs[mloc];
      float bb4[4] = {bv.x, bv.y, bv.z, bv.w};
#pragma unroll
      for (int ni = 0; ni < 4; ++ni) {
        const int n = n0 + wn * 64 + ni * 16 + lc;
        if (sel == 2) {
          u16* V = (u16*)O2 + (size_t)bz * sO;
#pragma unroll
          for (int q2 = 0; q2 < 4; ++q2) V[(size_t)(mloc + q2) * HW + n] = f2bf(acc[mi][ni][q2] + bb4[q2]);
        } else {
          u16* Oq = (u16*)(sel == 0 ? O0 : O1) + (size_t)bz * sO;
          u16x4 pk;
#pragma unroll
          for (int q2 = 0; q2 < 4; ++q2) pk[q2] = f2bf(acc[mi][ni][q2] + bb4[q2]);
          *(u16x4*)&Oq[(size_t)n * CCH + mloc] = pk;
        }
      }
    }
  } else {   // EPI == 2: fp32 out + bias + residual
    float* O = (float*)O0 + (size_t)bz * sO;
    const float* R = aux + (size_t)bz * sAux;
#pragma unroll
    for (int mi = 0; mi < 4; ++mi) {
      const int mb = m0 + wm * 64 + mi * 16 + lr4;
      float bb4[4] = {0.f, 0.f, 0.f, 0.f};
      if (HASB) {
        const float4 bv = *(const float4*)&b0[mb];
        bb4[0] = bv.x; bb4[1] = bv.y; bb4[2] = bv.z; bb4[3] = bv.w;
      }
#pragma unroll
      for (int ni = 0; ni < 4; ++ni) {
        const int n = n0 + wn * 64 + ni * 16 + lc;
#pragma unroll
        for (int q2 = 0; q2 < 4; ++q2)
          O[(size_t)(mb + q2) * ldo + n] = acc[mi][ni][q2] * scale + bb4[q2] + R[(size_t)(mb + q2) * ldo + n];
      }
    }
  }
}

// ---------------- fused flash attention: 4 waves, ITILE=64, KVBLK=32 ----------------
// Grid: 512 blocks x 256 thr. it=bid>>3 (64-row i-tile), b=(bid>>1)&3, jh=bid&1.
// Per t (32 j): S^T = mfma(K, Q) (each wave: 16 i-rows) -> exp(s/16-8) ->
// pack to P_block[64][32 j] -> barrier -> PV: wave w owns channels [w*64, w*64+64)
// for ALL 64 i rows. 2-phase dbuf K/V staging; ~69KB LDS -> 2 blocks/CU.
#define LBUFA 32768            // K 16KB | V 16KB per buffer
__global__ __launch_bounds__(256) void attn_fused(
    const u16* __restrict__ Qt, const u16* __restrict__ Kt, const u16* __restrict__ Vv,
    float* __restrict__ Opart, float* __restrict__ Rpart) {
  __shared__ __attribute__((aligned(16))) char lds[2 * LBUFA];        // 64KB
  __shared__ __attribute__((aligned(16))) unsigned P_block[64][20];   // 5KB, stride-20 dw
  const int bid = blockIdx.x;
  const int it = bid >> 3, b = (bid >> 1) & 3, jh = bid & 1;
  const int tid = threadIdx.x, w = tid >> 6, l = tid & 63;
  const int g = l >> 4, base = l & 15;
  const u16* Qb = Qt + (size_t)b * HW * CCH;
  const u16* Kb = Kt + (size_t)b * HW * CCH;
  const u16* Vb = Vv + (size_t)b * CCH * HW;
  const int iw0 = it * 64 + w * 16;

  // Q fragments: row = iw0 + base, k = kc*32 + g*8 + e
  bf16x8 q[8];
#pragma unroll
  for (int kc = 0; kc < 8; ++kc)
    q[kc] = *(const bf16x8*)&Qb[(size_t)(iw0 + base) * CCH + kc * 32 + g * 8];

  f32x4 oacc[4][4];   // [fi][cf]: O[it*64 + fi*16 + g*4 + r][w*64 + cf*16 + base]
#pragma unroll
  for (int fi = 0; fi < 4; ++fi)
#pragma unroll
    for (int cf = 0; cf < 4; ++cf)
#pragma unroll
      for (int r = 0; r < 4; ++r) oacc[fi][cf][r] = 0.f;
  float rsum = 0.f;

  auto stage = [&](int buf, int j0) {
    char* Kl = lds + buf * LBUFA;
    char* Vl = Kl + 16384;
#pragma unroll
    for (int s = 0; s < 8; ++s) {
      const int i = s * 4 + w;   // 0..31, wave-uniform
      if (i < 16) {
        // K-tile [32 rows][32 chunks of 16B], source-swizzled
        const int row = i * 2 + (l >> 5);
        const int c5 = l & 31;
        gload_lds16(Kb + (size_t)(j0 + row) * CCH + ((c5 ^ (row & 7)) * 8), Kl + i * 1024);
      } else {
        // V-tile [4 jg][256 c][16B]: slot (jg, cc) <- V[cc][j0 + jg*8 .. +7]
        const int jj = i - 16;
        const int jg = jj >> 2, sub = jj & 3;
        const int cc = sub * 64 + l;
        gload_lds16(Vb + (size_t)cc * HW + j0 + jg * 8, Vl + jg * 4096 + sub * 1024);
      }
    }
  };

  const int j0base = jh * 2048;
  const int NT = 64;   // 2048 / 32
  stage(0, j0base);
  asm volatile("s_waitcnt vmcnt(0)" ::: "memory");
  __builtin_amdgcn_s_barrier();

  for (int t = 0; t < NT; ++t) {
    const int cur = t & 1;
    if (t + 1 < NT) stage(cur ^ 1, j0base + (t + 1) * 32);
    const char* Kl = lds + cur * LBUFA;
    const char* Vl = Kl + 16384;
    // ---- S^T: 32 j x this wave's 16 i-rows, K=256 ----
    f32x4 sacc[2];
#pragma unroll
    for (int mj = 0; mj < 2; ++mj)
#pragma unroll
      for (int r = 0; r < 4; ++r) sacc[mj][r] = 0.f;
    __builtin_amdgcn_s_setprio(1);
#pragma unroll
    for (int kc = 0; kc < 8; ++kc) {
      bf16x8 kf[2];
#pragma unroll
      for (int mj = 0; mj < 2; ++mj) {
        const int row = mj * 16 + base;
        const int c5 = (kc * 4 + g) ^ (row & 7);
        kf[mj] = *(const bf16x8*)(Kl + row * 512 + c5 * 16);
      }
#pragma unroll
      for (int mj = 0; mj < 2; ++mj)
        sacc[mj] = __builtin_amdgcn_mfma_f32_16x16x32_bf16(kf[mj], q[kc], sacc[mj], 0, 0, 0);
    }
    __builtin_amdgcn_s_setprio(0);
    // ---- exp + pack; lane (g,base) holds P'[jloc = mj*16+4g+r][i = iw0+base] ----
    const int iL = w * 16 + base;
#pragma unroll
    for (int mj = 0; mj < 2; ++mj) {
      const float p0 = __expf(sacc[mj][0] * 0.0625f - 8.0f);
      const float p1 = __expf(sacc[mj][1] * 0.0625f - 8.0f);
      const float p2 = __expf(sacc[mj][2] * 0.0625f - 8.0f);
      const float p3 = __expf(sacc[mj][3] * 0.0625f - 8.0f);
      const u16 e0 = f2bf(p0), e1 = f2bf(p1), e2 = f2bf(p2), e3 = f2bf(p3);
      rsum += (bf2f(e0) + bf2f(e1)) + (bf2f(e2) + bf2f(e3));
      P_block[iL][mj * 8 + g * 2 + 0] = (unsigned)e0 | ((unsigned)e1 << 16);
      P_block[iL][mj * 8 + g * 2 + 1] = (unsigned)e2 | ((unsigned)e3 << 16);
    }
    asm volatile("s_waitcnt lgkmcnt(0)" ::: "memory");   // drain own P writes
    __builtin_amdgcn_sched_barrier(0);
    __builtin_amdgcn_s_barrier();                        // P_block visible to all waves
    // ---- PV: wave w computes O[all 64 i][w*64 .. +64) over this 32-j chunk ----
    bf16x8 vf[4];
#pragma unroll
    for (int cf = 0; cf < 4; ++cf)
      vf[cf] = *(const bf16x8*)(Vl + g * 4096 + (w * 64 + cf * 16 + base) * 16);
    __builtin_amdgcn_s_setprio(1);
#pragma unroll
    for (int fi = 0; fi < 4; ++fi) {
      const bf16x8 af = *(const bf16x8*)&P_block[fi * 16 + base][g * 4];
#pragma unroll
      for (int cf = 0; cf < 4; ++cf)
        oacc[fi][cf] = __builtin_amdgcn_mfma_f32_16x16x32_bf16(af, vf[cf], oacc[fi][cf], 0, 0, 0);
    }
    __builtin_amdgcn_s_setprio(0);
    asm volatile("s_waitcnt vmcnt(0) lgkmcnt(0)" ::: "memory");  // next tile staged; P reads done
    __builtin_amdgcn_sched_barrier(0);
    __builtin_amdgcn_s_barrier();
  }

  // ---- epilogue: row-sum partials + O partials (f32) ----
  rsum += __shfl_xor(rsum, 16);
  rsum += __shfl_xor(rsum, 32);
  if (l < 16) Rpart[(size_t)jh * 16384 + b * HW + iw0 + l] = rsum;
  float* Op = Opart + (size_t)jh * 16384 * CCH + (size_t)b * HW * CCH + (size_t)it * 64 * CCH;
#pragma unroll
  for (int fi = 0; fi < 4; ++fi) {
#pragma unroll
    for (int cf = 0; cf < 4; ++cf) {
      const int c = w * 64 + cf * 16 + base;
#pragma unroll
      for (int r = 0; r < 4; ++r)
        Op[(size_t)(fi * 16 + g * 4 + r) * CCH + c] = oacc[fi][cf][r];
    }
  }
}

// ---------------- combine: Ot = bf16((O0+O1) / (r0+r1)) ----------------
__global__ __launch_bounds__(256) void attn_combine(const float* __restrict__ Op,
                                                    const float* __restrict__ Rp,
                                                    u16* __restrict__ Ot) {
  const int idx = blockIdx.x * 256 + threadIdx.x;   // 1M threads
  const int row = idx >> 6;                         // b*4096 + i
  const int c4 = (idx & 63) * 4;
  const float4 o0 = *(const float4*)&Op[(size_t)row * CCH + c4];
  const float4 o1 = *(const float4*)&Op[(size_t)16384 * CCH + (size_t)row * CCH + c4];
  const float inv = 1.0f / (Rp[row] + Rp[16384 + row]);
  u16x4 r;
  r[0] = f2bf((o0.x + o1.x) * inv);
  r[1] = f2bf((o0.y + o1.y) * inv);
  r[2] = f2bf((o0.z + o1.z) * inv);
  r[3] = f2bf((o0.w + o1.w) * inv);
  *(u16x4*)&Ot[(size_t)row * CCH + c4] = r;
}

extern "C" void kernel_launch(void* const* d_in, const int* in_sizes, int n_in,
                              void* d_out, int out_size, void* d_ws, size_t ws_size,
                              hipStream_t stream) {
  const float* x   = (const float*)d_in[0];
  const float* gsc = (const float*)d_in[1];
  const float* gbi = (const float*)d_in[2];
  const float* wq  = (const float*)d_in[3];
  const float* bq  = (const float*)d_in[4];
  const float* wk  = (const float*)d_in[5];
  const float* bk  = (const float*)d_in[6];
  const float* wv  = (const float*)d_in[7];
  const float* bv  = (const float*)d_in[8];
  const float* wp  = (const float*)d_in[9];
  const float* bp  = (const float*)d_in[10];
  float* out = (float*)d_out;

  char* ws = (char*)d_ws;
  size_t off = 0;
  auto alloc = [&](size_t bytes) {
    size_t o = off; off = (off + bytes + 255) & ~(size_t)255; return o;
  };
  const size_t szMat = (size_t)NBATCH * HW * CCH * 2;   // 8.4MB
  u16* W      = (u16*)(ws + alloc(4 * 65536 * 2));
  float* pgn  = (float*)(ws + alloc(16 * 32 * 2 * 4));
  float2* st  = (float2*)(ws + alloc(16 * 8));
  u16* Ht = (u16*)(ws + alloc(szMat));
  u16* Qt = (u16*)(ws + alloc(szMat));
  u16* Kt = (u16*)(ws + alloc(szMat));
  u16* Vv = (u16*)(ws + alloc(szMat));
  u16* Ot = (u16*)(ws + alloc(szMat));
  float* Opart = (float*)(ws + alloc((size_t)2 * 16384 * CCH * 4));  // 33.5MB
  float* Rpart = (float*)(ws + alloc((size_t)2 * 16384 * 4));        // 128KB

  const long sM = (long)HW * CCH;

  wcast<<<dim3(32, 4), 256, 0, stream>>>(wq, wk, wv, wp, W);
  gn_partial<<<dim3(32, 16), 256, 0, stream>>>(x, pgn);
  gn_finalize<<<1, 64, 0, stream>>>(pgn, st);
  norm_tr<<<dim3(HW / 64, CCH / 64, NBATCH), 256, 0, stream>>>(x, st, gsc, gbi, Ht);

  // fused QKV: A = [Wq;Wk;Wv] (768x256), B = Ht -> Qt [i][c], Kt [j][c], Vv [c][j]
  gemm2<5, true><<<dim3(32, 6, NBATCH), 256, 0, stream>>>(
      W, 256, 0, Ht, 256, sM, Qt, 256, sM, Kt, Vv, bq, bk, bv, nullptr, 0, 1.f, 256);

  // fused attention: 512 blocks (64 i-tiles x 4 b x 2 jh), 256 threads
  attn_fused<<<512, 256, 0, stream>>>(Qt, Kt, Vv, Opart, Rpart);
  attn_combine<<<4096, 256, 0, stream>>>(Opart, Rpart, Ot);

  // out[c][i] = Wp . Ot^T + bp + x
  gemm2<2, true><<<dim3(32, 2, NBATCH), 256, 0, stream>>>(
      W + 3 * 65536, 256, 0, Ot, 256, sM, out, HW, (long)CCH * HW, nullptr, nullptr,
      bp, nullptr, nullptr, x, (long)CCH * HW, 1.f, 256);
}